// Round 4
// baseline (868.643 us; speedup 1.0000x reference)
//
#include <hip/hip_runtime.h>
#include <float.h>

// PretrainingGIN on MI355X — Round 4.
// R3 post-mortem: gather is beyond-L2 fetch-bound (283MB @1.9TB/s); the
// per-layer pointer chase added nxt traffic and killed load ILP.
// Changes:
//  - Hybrid CSR: linked-list build (+deg count) -> scan -> per-node chase-fill
//    writing contiguous 64B src bursts (one-time cost, coalesced writes).
//  - Fused agg+MLP kernel: wave gathers its 16 rows (8-deep CSR loads) into
//    LDS, then runs both bf16 MFMA GEMMs wave-private; one barrier; coalesced
//    store. Removes the m round-trip and hides MFMA under gather BW.

#define N_NODES 100000
#define N_EDGES 1600000
#define DIM 128
#define NGRAPHS 64

#define SCAN_T 256
#define SCAN_ITEMS 4
#define SCAN_CHUNK 1024
#define SCAN_NB ((N_NODES + SCAN_CHUNK - 1) / SCAN_CHUNK)   // 98

#define BROWS 64           // rows per fused block (1 row-tile of 16 per wave)
#define LSTRIDE 136        // bf16 elems; 272B rows keep 16B align

typedef __attribute__((ext_vector_type(8))) short bf16x8;
typedef __attribute__((ext_vector_type(4))) float f32x4;

__device__ inline float bflo(unsigned u) { return __uint_as_float(u << 16); }
__device__ inline float bfhi(unsigned u) { return __uint_as_float(u & 0xffff0000u); }

__device__ inline unsigned short f2bf(float a) {      // RNE
    unsigned u = __float_as_uint(a);
    u = u + 0x7fff + ((u >> 16) & 1);
    return (unsigned short)(u >> 16);
}
__device__ inline unsigned f2bf_pack(float a, float b) {
    unsigned ua = __float_as_uint(a), ub = __float_as_uint(b);
    ua = ua + 0x7fff + ((ua >> 16) & 1);
    ub = ub + 0x7fff + ((ub >> 16) & 1);
    return (ua >> 16) | (ub & 0xffff0000u);
}

// ---------------- CSR build: list -> deg/scan -> chase-fill ----------------
__global__ void k_init(int* __restrict__ head, int* __restrict__ deg) {
    int i = blockIdx.x * blockDim.x + threadIdx.x;
    if (i < N_NODES) { head[i] = -1; deg[i] = 0; }
}

__global__ void k_build(const int* __restrict__ src, const int* __restrict__ dst,
                        int* __restrict__ head, int* __restrict__ deg,
                        int2* __restrict__ nxt) {
    int e = blockIdx.x * blockDim.x + threadIdx.x;
    if (e < N_EDGES) {
        int d = dst[e];
        atomicAdd(&deg[d], 1);
        int old = atomicExch(&head[d], e);
        nxt[e] = make_int2(old, src[e]);   // sequential 8B writes
    }
}

__global__ void k_scan1(const int* __restrict__ deg, int* __restrict__ offs,
                        int* __restrict__ bsum) {
    __shared__ int s[SCAN_T];
    int b = blockIdx.x, t = threadIdx.x;
    int base = b * SCAN_CHUNK + t * SCAN_ITEMS;
    int v[SCAN_ITEMS];
    int tot = 0;
#pragma unroll
    for (int j = 0; j < SCAN_ITEMS; ++j) {
        int i = base + j;
        v[j] = (i < N_NODES) ? deg[i] : 0;
        tot += v[j];
    }
    s[t] = tot;
    __syncthreads();
    for (int off = 1; off < SCAN_T; off <<= 1) {
        int x = (t >= off) ? s[t - off] : 0;
        __syncthreads();
        s[t] += x;
        __syncthreads();
    }
    int run = s[t] - tot;
    if (t == SCAN_T - 1) bsum[b] = s[t];
#pragma unroll
    for (int j = 0; j < SCAN_ITEMS; ++j) {
        int i = base + j;
        if (i < N_NODES) offs[i] = run;
        run += v[j];
    }
}

__global__ void k_scan2(int* __restrict__ bsum) {
    __shared__ int s[256];
    int t = threadIdx.x;
    int v = (t < SCAN_NB) ? bsum[t] : 0;
    s[t] = v;
    __syncthreads();
    for (int off = 1; off < 256; off <<= 1) {
        int x = (t >= off) ? s[t - off] : 0;
        __syncthreads();
        s[t] += x;
        __syncthreads();
    }
    if (t < SCAN_NB) bsum[t] = s[t] - v;
}

__global__ void k_scan3(int* __restrict__ offs, const int* __restrict__ bsum) {
    int i = blockIdx.x * blockDim.x + threadIdx.x;
    if (i < N_NODES) offs[i] = offs[i] + bsum[i / SCAN_CHUNK];
    if (i == 0) offs[N_NODES] = N_EDGES;
}

// lane-per-node chase; each node writes its ~16 srcs as one contiguous burst.
__global__ void k_fill(const int* __restrict__ head, const int2* __restrict__ nxt,
                       const int* __restrict__ offs, int* __restrict__ ssrc) {
    int nd = blockIdx.x * blockDim.x + threadIdx.x;
    if (nd >= N_NODES) return;
    int e = head[nd];
    int p = offs[nd];
    while (e >= 0) {
        int2 v = nxt[e];
        ssrc[p++] = v.y;
        e = v.x;
    }
}

// ---------------- dtype prep ----------------
__global__ void k_cast(const float* __restrict__ x, unsigned short* __restrict__ y) {
    int i = (blockIdx.x * blockDim.x + threadIdx.x) * 4;
    if (i < N_NODES * DIM) {
        float4 v = *(const float4*)(x + i);
        uint2 o;
        o.x = f2bf_pack(v.x, v.y);
        o.y = f2bf_pack(v.z, v.w);
        *(uint2*)(y + i) = o;
    }
}

// Repack W (k-major 128x128 fp32) into B-fragment order bf16:
// pack[mat][kb*4096 + c*32 + q*8 + j] = W[mat][(kb*32 + q*8 + j)*128 + c]
__global__ void k_pack(const float* __restrict__ W1, const float* __restrict__ W2,
                       unsigned short* __restrict__ pack) {
    int tid = blockIdx.x * blockDim.x + threadIdx.x;
    if (tid >= 6 * DIM * DIM) return;
    int mat = tid >> 14;
    int e = tid & 16383;
    int k = e >> 7, c = e & 127;
    const float* W = (mat < 3) ? (W1 + mat * DIM * DIM) : (W2 + (mat - 3) * DIM * DIM);
    int kb = k >> 5, q = (k >> 3) & 3, j = k & 7;
    pack[mat * DIM * DIM + kb * 4096 + c * 32 + q * 8 + j] = f2bf(W[k * DIM + c]);
}

// ---------------- fused layer: h_out = MLP(h + sum_{j->i} h_j) ----------------
// Block = 64 rows, 4 waves; wave owns rows wv*16..wv*16+15 end-to-end
// (gather -> A1 -> GEMM1 -> t -> GEMM2 -> out), all in one 17.4KB LDS buffer.
// Only barrier is before the final coalesced store. Reads h, writes hout
// (must be distinct buffers).
__global__ __launch_bounds__(256) void k_fused(const unsigned short* __restrict__ h,
                                               const int* __restrict__ offs,
                                               const int* __restrict__ ssrc,
                                               unsigned short* __restrict__ hout,
                                               const unsigned short* __restrict__ Wp1,
                                               const float* __restrict__ b1,
                                               const unsigned short* __restrict__ Wp2,
                                               const float* __restrict__ b2,
                                               int relu_out) {
    __shared__ unsigned short buf[BROWS * LSTRIDE];   // 17408 B
    const int tid = threadIdx.x;
    const int wv = tid >> 6, lane = tid & 63;
    const int q = lane >> 4, n = lane & 15;
    const int row0 = blockIdx.x * BROWS;

    // ---- gather: wave computes its 16 m-rows into LDS (wave-private) ----
    const int col = lane * 2;
#pragma unroll 1
    for (int i = 0; i < 16; ++i) {
        int node = row0 + wv * 16 + i;
        float ax = 0.f, ay = 0.f;
        if (node < N_NODES) {
            unsigned u = *(const unsigned*)(h + (size_t)node * DIM + col);
            ax = bflo(u); ay = bfhi(u);
            int e0 = offs[node], e1 = offs[node + 1];
            int e = e0;
            for (; e + 8 <= e1; e += 8) {     // 8 rows in flight
                int s0 = ssrc[e],     s1 = ssrc[e + 1], s2 = ssrc[e + 2], s3 = ssrc[e + 3];
                int s4 = ssrc[e + 4], s5 = ssrc[e + 5], s6 = ssrc[e + 6], s7 = ssrc[e + 7];
                unsigned v0 = *(const unsigned*)(h + (size_t)s0 * DIM + col);
                unsigned v1 = *(const unsigned*)(h + (size_t)s1 * DIM + col);
                unsigned v2 = *(const unsigned*)(h + (size_t)s2 * DIM + col);
                unsigned v3 = *(const unsigned*)(h + (size_t)s3 * DIM + col);
                unsigned v4 = *(const unsigned*)(h + (size_t)s4 * DIM + col);
                unsigned v5 = *(const unsigned*)(h + (size_t)s5 * DIM + col);
                unsigned v6 = *(const unsigned*)(h + (size_t)s6 * DIM + col);
                unsigned v7 = *(const unsigned*)(h + (size_t)s7 * DIM + col);
                ax += (bflo(v0) + bflo(v1)) + (bflo(v2) + bflo(v3)) +
                      (bflo(v4) + bflo(v5)) + (bflo(v6) + bflo(v7));
                ay += (bfhi(v0) + bfhi(v1)) + (bfhi(v2) + bfhi(v3)) +
                      (bfhi(v4) + bfhi(v5)) + (bfhi(v6) + bfhi(v7));
            }
            for (; e + 2 <= e1; e += 2) {
                int s0 = ssrc[e], s1 = ssrc[e + 1];
                unsigned v0 = *(const unsigned*)(h + (size_t)s0 * DIM + col);
                unsigned v1 = *(const unsigned*)(h + (size_t)s1 * DIM + col);
                ax += bflo(v0) + bflo(v1);
                ay += bfhi(v0) + bfhi(v1);
            }
            if (e < e1) {
                unsigned v = *(const unsigned*)(h + (size_t)ssrc[e] * DIM + col);
                ax += bflo(v); ay += bfhi(v);
            }
        }
        *(unsigned*)&buf[(wv * 16 + i) * LSTRIDE + col] = f2bf_pack(ax, ay);
    }

    // ---- A1 fragments from own LDS rows (lgkmcnt-ordered, no barrier) ----
    bf16x8 a1[4];
    {
        const unsigned short* mr = buf + (wv * 16 + n) * LSTRIDE + q * 8;
#pragma unroll
        for (int kb = 0; kb < 4; ++kb) a1[kb] = *(const bf16x8*)(mr + kb * 32);
    }

    float bia1[8], bia2[8];
#pragma unroll
    for (int ct = 0; ct < 8; ++ct) {
        bia1[ct] = b1[ct * 16 + n];
        bia2[ct] = b2[ct * 16 + n];
    }

    // ---- GEMM1: t = relu(m@W1 + b1), overwrite own LDS rows ----
#pragma unroll
    for (int ct = 0; ct < 8; ++ct) {
        f32x4 acc = {0.f, 0.f, 0.f, 0.f};
#pragma unroll
        for (int kb = 0; kb < 4; ++kb) {
            bf16x8 b = *(const bf16x8*)(Wp1 + kb * 4096 + (ct * 16 + n) * 32 + q * 8);
            acc = __builtin_amdgcn_mfma_f32_16x16x32_bf16(a1[kb], b, acc, 0, 0, 0);
        }
#pragma unroll
        for (int r = 0; r < 4; ++r)
            buf[(wv * 16 + q * 4 + r) * LSTRIDE + ct * 16 + n] =
                f2bf(fmaxf(acc[r] + bia1[ct], 0.f));
    }

    // ---- A2 fragments ----
    bf16x8 a2[4];
    {
        const unsigned short* tr = buf + (wv * 16 + n) * LSTRIDE + q * 8;
#pragma unroll
        for (int kb = 0; kb < 4; ++kb) a2[kb] = *(const bf16x8*)(tr + kb * 32);
    }

    // ---- GEMM2: out = t@W2 + b2, overwrite own LDS rows ----
#pragma unroll
    for (int ct = 0; ct < 8; ++ct) {
        f32x4 acc = {0.f, 0.f, 0.f, 0.f};
#pragma unroll
        for (int kb = 0; kb < 4; ++kb) {
            bf16x8 b = *(const bf16x8*)(Wp2 + kb * 4096 + (ct * 16 + n) * 32 + q * 8);
            acc = __builtin_amdgcn_mfma_f32_16x16x32_bf16(a2[kb], b, acc, 0, 0, 0);
        }
#pragma unroll
        for (int r = 0; r < 4; ++r) {
            float v = acc[r] + bia2[ct];
            if (relu_out) v = fmaxf(v, 0.f);
            buf[(wv * 16 + q * 4 + r) * LSTRIDE + ct * 16 + n] = f2bf(v);
        }
    }
    __syncthreads();

    // ---- coalesced store: thread -> row tid>>2, 32-col quarter ----
    {
        int r = tid >> 2;
        int c0 = (tid & 3) * 32;
        int grow = row0 + r;
        if (grow < N_NODES) {
            unsigned short* dp = hout + (size_t)grow * DIM + c0;
            const unsigned short* sp = buf + r * LSTRIDE + c0;
#pragma unroll
            for (int s8 = 0; s8 < 4; ++s8)
                *(bf16x8*)(dp + s8 * 8) = *(const bf16x8*)(sp + s8 * 8);
        }
    }
}

// ---------------- pool ----------------
__global__ void k_starts(const int* __restrict__ batch, int* __restrict__ starts) {
    int g = threadIdx.x;
    if (g > NGRAPHS) return;
    int lo = 0, hi = N_NODES;
    while (lo < hi) {
        int mid = (lo + hi) >> 1;
        if (batch[mid] < g) lo = mid + 1;
        else hi = mid;
    }
    starts[g] = lo;
}

__global__ __launch_bounds__(256) void k_pool(const unsigned short* __restrict__ h,
                                              const int* __restrict__ starts,
                                              float* __restrict__ out) {
    __shared__ float red[4][DIM];
    int g = blockIdx.x;
    int t = threadIdx.x;
    int rowpar = t >> 6;
    int col = (t & 63) * 2;
    int i0 = starts[g], i1 = starts[g + 1];
    float mx = -FLT_MAX, my = -FLT_MAX;
    for (int i = i0 + rowpar; i < i1; i += 4) {
        unsigned u = *(const unsigned*)(h + (size_t)i * DIM + col);
        mx = fmaxf(mx, bflo(u));
        my = fmaxf(my, bfhi(u));
    }
    red[rowpar][col] = mx;
    red[rowpar][col + 1] = my;
    __syncthreads();
    if (rowpar == 0) {
        mx = fmaxf(fmaxf(red[0][col], red[1][col]), fmaxf(red[2][col], red[3][col]));
        my = fmaxf(fmaxf(red[0][col + 1], red[1][col + 1]),
                   fmaxf(red[2][col + 1], red[3][col + 1]));
        out[g * DIM + col] = mx;
        out[g * DIM + col + 1] = my;
    }
}

extern "C" void kernel_launch(void* const* d_in, const int* in_sizes, int n_in,
                              void* d_out, int out_size, void* d_ws, size_t ws_size,
                              hipStream_t stream) {
    const float* x   = (const float*)d_in[0];
    const int* ei    = (const int*)d_in[1];
    const int* batch = (const int*)d_in[2];
    const float* W1  = (const float*)d_in[3];
    const float* b1  = (const float*)d_in[4];
    const float* W2  = (const float*)d_in[5];
    const float* b2  = (const float*)d_in[6];
    float* out = (float*)d_out;

    const int* src = ei;
    const int* dst = ei + N_EDGES;

    unsigned short* hA  = (unsigned short*)d_ws;                  // 25.6 MB
    unsigned short* hB  = hA + (size_t)N_NODES * DIM;             // 25.6 MB
    int2* nxt           = (int2*)(hB + (size_t)N_NODES * DIM);    // 12.8 MB
    int* sorted_src     = (int*)(nxt + N_EDGES);                  // 6.4 MB
    int* head           = sorted_src + N_EDGES;                   // 400 KB
    int* deg            = head + N_NODES;                         // 400 KB
    int* offs           = deg + N_NODES;                          // 400 KB
    int* bsum           = offs + (N_NODES + 1);                   // 98
    unsigned short* wpk = (unsigned short*)(bsum + SCAN_NB);      // 192 KB
    int* starts         = (int*)(wpk + 6 * DIM * DIM);            // 65

    // CSR build: list -> deg -> scan -> chase-fill (contiguous bursts)
    k_init<<<(N_NODES + 255) / 256, 256, 0, stream>>>(head, deg);
    k_build<<<(N_EDGES + 255) / 256, 256, 0, stream>>>(src, dst, head, deg, nxt);
    k_scan1<<<SCAN_NB, SCAN_T, 0, stream>>>(deg, offs, bsum);
    k_scan2<<<1, 256, 0, stream>>>(bsum);
    k_scan3<<<(N_NODES + 255) / 256, 256, 0, stream>>>(offs, bsum);
    k_fill<<<(N_NODES + 255) / 256, 256, 0, stream>>>(head, nxt, offs, sorted_src);

    // dtype prep
    k_cast<<<(N_NODES * DIM / 4 + 255) / 256, 256, 0, stream>>>(x, hA);
    k_pack<<<(6 * DIM * DIM + 255) / 256, 256, 0, stream>>>(W1, W2, wpk);

    const int fusedBlocks = (N_NODES + BROWS - 1) / BROWS;   // 1563
    unsigned short* Wp1 = wpk;
    unsigned short* Wp2 = wpk + 3 * DIM * DIM;

    // 3 fused layers, ping-pong hA <-> hB
    k_fused<<<fusedBlocks, 256, 0, stream>>>(hA, offs, sorted_src, hB,
                                             Wp1, b1, Wp2, b2, 1);
    k_fused<<<fusedBlocks, 256, 0, stream>>>(hB, offs, sorted_src, hA,
                                             Wp1 + DIM * DIM, b1 + DIM,
                                             Wp2 + DIM * DIM, b2 + DIM, 1);
    k_fused<<<fusedBlocks, 256, 0, stream>>>(hA, offs, sorted_src, hB,
                                             Wp1 + 2 * DIM * DIM, b1 + 2 * DIM,
                                             Wp2 + 2 * DIM * DIM, b2 + 2 * DIM, 0);

    // pool
    k_starts<<<1, 128, 0, stream>>>(batch, starts);
    k_pool<<<NGRAPHS, 256, 0, stream>>>(hB, starts, out);
}

// Round 5
// 802.082 us; speedup vs baseline: 1.0830x; 1.0830x over previous
//
#include <hip/hip_runtime.h>
#include <float.h>

// PretrainingGIN on MI355X — Round 5.
// R4 post-mortem: fused layer was concurrency-starved (25% occ, 1.38 TB/s vs
// 1.9 achievable on this random-gather pattern); build chain (3.2M atomics +
// chase) cost more than R2's counting sort.
// Changes:
//  - k_fused: 2-wave (128-thr) blocks, ZERO barriers — each wave owns 16 rows
//    end-to-end (gather -> GEMM1 -> GEMM2 -> store own rows). Wave-private LDS
//    only; max residency for gather MLP overlap. 100000 = 3125 * 32 exactly,
//    so no bounds checks anywhere.
//  - ELL adjacency build: zero(deg) + one kernel (atomicAdd slot + write).
//    Replaces list build + scan + chase-fill. Width 64 >> max in-degree (~45).

#define N_NODES 100000
#define N_EDGES 1600000
#define DIM 128
#define NGRAPHS 64
#define ELLW 64

#define BROWS 32           // rows per fused block (16 per wave, 2 waves)
#define LSTRIDE 136        // bf16 elems; 272B rows keep 16B align

typedef __attribute__((ext_vector_type(8))) short bf16x8;
typedef __attribute__((ext_vector_type(4))) float f32x4;

__device__ inline float bflo(unsigned u) { return __uint_as_float(u << 16); }
__device__ inline float bfhi(unsigned u) { return __uint_as_float(u & 0xffff0000u); }

__device__ inline unsigned short f2bf(float a) {      // RNE
    unsigned u = __float_as_uint(a);
    u = u + 0x7fff + ((u >> 16) & 1);
    return (unsigned short)(u >> 16);
}
__device__ inline unsigned f2bf_pack(float a, float b) {
    unsigned ua = __float_as_uint(a), ub = __float_as_uint(b);
    ua = ua + 0x7fff + ((ua >> 16) & 1);
    ub = ub + 0x7fff + ((ub >> 16) & 1);
    return (ua >> 16) | (ub & 0xffff0000u);
}

// ---------------- ELL adjacency build ----------------
__global__ void k_zero_deg(int* __restrict__ deg) {
    int i = blockIdx.x * blockDim.x + threadIdx.x;
    if (i < N_NODES) deg[i] = 0;
}

__global__ void k_ell(const int* __restrict__ src, const int* __restrict__ dst,
                      int* __restrict__ deg, int* __restrict__ ell) {
    int e = blockIdx.x * blockDim.x + threadIdx.x;
    if (e < N_EDGES) {
        int d = dst[e];
        int slot = atomicAdd(&deg[d], 1);
        if (slot < ELLW) ell[d * ELLW + slot] = src[e];
    }
}

// ---------------- dtype prep ----------------
__global__ void k_cast(const float* __restrict__ x, unsigned short* __restrict__ y) {
    int i = (blockIdx.x * blockDim.x + threadIdx.x) * 4;
    if (i < N_NODES * DIM) {
        float4 v = *(const float4*)(x + i);
        uint2 o;
        o.x = f2bf_pack(v.x, v.y);
        o.y = f2bf_pack(v.z, v.w);
        *(uint2*)(y + i) = o;
    }
}

// Repack W (k-major 128x128 fp32) into B-fragment order bf16:
// pack[mat][kb*4096 + c*32 + q*8 + j] = W[mat][(kb*32 + q*8 + j)*128 + c]
__global__ void k_pack(const float* __restrict__ W1, const float* __restrict__ W2,
                       unsigned short* __restrict__ pack) {
    int tid = blockIdx.x * blockDim.x + threadIdx.x;
    if (tid >= 6 * DIM * DIM) return;
    int mat = tid >> 14;
    int e = tid & 16383;
    int k = e >> 7, c = e & 127;
    const float* W = (mat < 3) ? (W1 + mat * DIM * DIM) : (W2 + (mat - 3) * DIM * DIM);
    int kb = k >> 5, q = (k >> 3) & 3, j = k & 7;
    pack[mat * DIM * DIM + kb * 4096 + c * 32 + q * 8 + j] = f2bf(W[k * DIM + c]);
}

// ---------------- fused layer: h_out = MLP(h + sum_{j->i} h_j) ----------------
// 128 threads = 2 waves; wave wv owns LDS rows wv*16..wv*16+15 and the same
// global rows. No __syncthreads anywhere: all LDS traffic is wave-private and
// ordered by the compiler's lgkmcnt insertion.
__global__ __launch_bounds__(128) void k_fused(const unsigned short* __restrict__ h,
                                               const int* __restrict__ deg,
                                               const int* __restrict__ ell,
                                               unsigned short* __restrict__ hout,
                                               const unsigned short* __restrict__ Wp1,
                                               const float* __restrict__ b1,
                                               const unsigned short* __restrict__ Wp2,
                                               const float* __restrict__ b2,
                                               int relu_out) {
    __shared__ unsigned short buf[BROWS * LSTRIDE];   // 8704 B
    const int tid = threadIdx.x;
    const int wv = tid >> 6, lane = tid & 63;
    const int q = lane >> 4, n = lane & 15;
    const int row0 = blockIdx.x * BROWS;

    // ---- gather: wave computes its 16 m-rows into LDS ----
    const int col = lane * 2;
#pragma unroll 1
    for (int i = 0; i < 16; ++i) {
        int node = row0 + wv * 16 + i;                 // wave-uniform
        unsigned u = *(const unsigned*)(h + (size_t)node * DIM + col);
        float ax = bflo(u), ay = bfhi(u);
        int dg = deg[node];
        if (dg > ELLW) dg = ELLW;
        const int* er = ell + node * ELLW;
        int e = 0;
        for (; e + 8 <= dg; e += 8) {                  // 8 rows in flight
            int s0 = er[e],     s1 = er[e + 1], s2 = er[e + 2], s3 = er[e + 3];
            int s4 = er[e + 4], s5 = er[e + 5], s6 = er[e + 6], s7 = er[e + 7];
            unsigned v0 = *(const unsigned*)(h + (size_t)s0 * DIM + col);
            unsigned v1 = *(const unsigned*)(h + (size_t)s1 * DIM + col);
            unsigned v2 = *(const unsigned*)(h + (size_t)s2 * DIM + col);
            unsigned v3 = *(const unsigned*)(h + (size_t)s3 * DIM + col);
            unsigned v4 = *(const unsigned*)(h + (size_t)s4 * DIM + col);
            unsigned v5 = *(const unsigned*)(h + (size_t)s5 * DIM + col);
            unsigned v6 = *(const unsigned*)(h + (size_t)s6 * DIM + col);
            unsigned v7 = *(const unsigned*)(h + (size_t)s7 * DIM + col);
            ax += (bflo(v0) + bflo(v1)) + (bflo(v2) + bflo(v3)) +
                  (bflo(v4) + bflo(v5)) + (bflo(v6) + bflo(v7));
            ay += (bfhi(v0) + bfhi(v1)) + (bfhi(v2) + bfhi(v3)) +
                  (bfhi(v4) + bfhi(v5)) + (bfhi(v6) + bfhi(v7));
        }
        for (; e + 2 <= dg; e += 2) {
            int s0 = er[e], s1 = er[e + 1];
            unsigned v0 = *(const unsigned*)(h + (size_t)s0 * DIM + col);
            unsigned v1 = *(const unsigned*)(h + (size_t)s1 * DIM + col);
            ax += bflo(v0) + bflo(v1);
            ay += bfhi(v0) + bfhi(v1);
        }
        if (e < dg) {
            unsigned v = *(const unsigned*)(h + (size_t)er[e] * DIM + col);
            ax += bflo(v); ay += bfhi(v);
        }
        *(unsigned*)&buf[(wv * 16 + i) * LSTRIDE + col] = f2bf_pack(ax, ay);
    }

    // ---- A1 fragments from own LDS rows ----
    bf16x8 a1[4];
    {
        const unsigned short* mr = buf + (wv * 16 + n) * LSTRIDE + q * 8;
#pragma unroll
        for (int kb = 0; kb < 4; ++kb) a1[kb] = *(const bf16x8*)(mr + kb * 32);
    }

    float bia1[8], bia2[8];
#pragma unroll
    for (int ct = 0; ct < 8; ++ct) {
        bia1[ct] = b1[ct * 16 + n];
        bia2[ct] = b2[ct * 16 + n];
    }

    // ---- GEMM1: t = relu(m@W1 + b1), overwrite own LDS rows ----
#pragma unroll
    for (int ct = 0; ct < 8; ++ct) {
        f32x4 acc = {0.f, 0.f, 0.f, 0.f};
#pragma unroll
        for (int kb = 0; kb < 4; ++kb) {
            bf16x8 b = *(const bf16x8*)(Wp1 + kb * 4096 + (ct * 16 + n) * 32 + q * 8);
            acc = __builtin_amdgcn_mfma_f32_16x16x32_bf16(a1[kb], b, acc, 0, 0, 0);
        }
#pragma unroll
        for (int r = 0; r < 4; ++r)
            buf[(wv * 16 + q * 4 + r) * LSTRIDE + ct * 16 + n] =
                f2bf(fmaxf(acc[r] + bia1[ct], 0.f));
    }

    // ---- A2 fragments ----
    bf16x8 a2[4];
    {
        const unsigned short* tr = buf + (wv * 16 + n) * LSTRIDE + q * 8;
#pragma unroll
        for (int kb = 0; kb < 4; ++kb) a2[kb] = *(const bf16x8*)(tr + kb * 32);
    }

    // ---- GEMM2: out = t@W2 + b2, overwrite own LDS rows ----
#pragma unroll
    for (int ct = 0; ct < 8; ++ct) {
        f32x4 acc = {0.f, 0.f, 0.f, 0.f};
#pragma unroll
        for (int kb = 0; kb < 4; ++kb) {
            bf16x8 b = *(const bf16x8*)(Wp2 + kb * 4096 + (ct * 16 + n) * 32 + q * 8);
            acc = __builtin_amdgcn_mfma_f32_16x16x32_bf16(a2[kb], b, acc, 0, 0, 0);
        }
#pragma unroll
        for (int r = 0; r < 4; ++r) {
            float v = acc[r] + bia2[ct];
            if (relu_out) v = fmaxf(v, 0.f);
            buf[(wv * 16 + q * 4 + r) * LSTRIDE + ct * 16 + n] = f2bf(v);
        }
    }

    // ---- store own wave's 16 rows, coalesced (no barrier needed) ----
    {
#pragma unroll
        for (int s = 0; s < 4; ++s) {
            int lr = wv * 16 + s * 4 + (lane >> 4);   // local row
            int c0 = (lane & 15) * 8;
            *(bf16x8*)(hout + (size_t)(row0 + lr) * DIM + c0) =
                *(const bf16x8*)(buf + lr * LSTRIDE + c0);
        }
    }
}

// ---------------- pool ----------------
__global__ void k_starts(const int* __restrict__ batch, int* __restrict__ starts) {
    int g = threadIdx.x;
    if (g > NGRAPHS) return;
    int lo = 0, hi = N_NODES;
    while (lo < hi) {
        int mid = (lo + hi) >> 1;
        if (batch[mid] < g) lo = mid + 1;
        else hi = mid;
    }
    starts[g] = lo;
}

__global__ __launch_bounds__(256) void k_pool(const unsigned short* __restrict__ h,
                                              const int* __restrict__ starts,
                                              float* __restrict__ out) {
    __shared__ float red[4][DIM];
    int g = blockIdx.x;
    int t = threadIdx.x;
    int rowpar = t >> 6;
    int col = (t & 63) * 2;
    int i0 = starts[g], i1 = starts[g + 1];
    float mx = -FLT_MAX, my = -FLT_MAX;
    for (int i = i0 + rowpar; i < i1; i += 4) {
        unsigned u = *(const unsigned*)(h + (size_t)i * DIM + col);
        mx = fmaxf(mx, bflo(u));
        my = fmaxf(my, bfhi(u));
    }
    red[rowpar][col] = mx;
    red[rowpar][col + 1] = my;
    __syncthreads();
    if (rowpar == 0) {
        mx = fmaxf(fmaxf(red[0][col], red[1][col]), fmaxf(red[2][col], red[3][col]));
        my = fmaxf(fmaxf(red[0][col + 1], red[1][col + 1]),
                   fmaxf(red[2][col + 1], red[3][col + 1]));
        out[g * DIM + col] = mx;
        out[g * DIM + col + 1] = my;
    }
}

extern "C" void kernel_launch(void* const* d_in, const int* in_sizes, int n_in,
                              void* d_out, int out_size, void* d_ws, size_t ws_size,
                              hipStream_t stream) {
    const float* x   = (const float*)d_in[0];
    const int* ei    = (const int*)d_in[1];
    const int* batch = (const int*)d_in[2];
    const float* W1  = (const float*)d_in[3];
    const float* b1  = (const float*)d_in[4];
    const float* W2  = (const float*)d_in[5];
    const float* b2  = (const float*)d_in[6];
    float* out = (float*)d_out;

    const int* src = ei;
    const int* dst = ei + N_EDGES;

    unsigned short* hA  = (unsigned short*)d_ws;                  // 25.6 MB
    unsigned short* hB  = hA + (size_t)N_NODES * DIM;             // 25.6 MB
    int* ell            = (int*)(hB + (size_t)N_NODES * DIM);     // 25.6 MB
    int* deg            = ell + (size_t)N_NODES * ELLW;           // 400 KB
    unsigned short* wpk = (unsigned short*)(deg + N_NODES);       // 192 KB
    int* starts         = (int*)(wpk + 6 * DIM * DIM);            // 65

    // ELL build
    k_zero_deg<<<(N_NODES + 255) / 256, 256, 0, stream>>>(deg);
    k_ell<<<(N_EDGES + 255) / 256, 256, 0, stream>>>(src, dst, deg, ell);

    // dtype prep
    k_cast<<<(N_NODES * DIM / 4 + 255) / 256, 256, 0, stream>>>(x, hA);
    k_pack<<<(6 * DIM * DIM + 255) / 256, 256, 0, stream>>>(W1, W2, wpk);

    const int fusedBlocks = N_NODES / BROWS;   // 3125 exactly
    unsigned short* Wp1 = wpk;
    unsigned short* Wp2 = wpk + 3 * DIM * DIM;

    // 3 fused layers, ping-pong hA <-> hB
    k_fused<<<fusedBlocks, 128, 0, stream>>>(hA, deg, ell, hB,
                                             Wp1, b1, Wp2, b2, 1);
    k_fused<<<fusedBlocks, 128, 0, stream>>>(hB, deg, ell, hA,
                                             Wp1 + DIM * DIM, b1 + DIM,
                                             Wp2 + DIM * DIM, b2 + DIM, 1);
    k_fused<<<fusedBlocks, 128, 0, stream>>>(hA, deg, ell, hB,
                                             Wp1 + 2 * DIM * DIM, b1 + 2 * DIM,
                                             Wp2 + 2 * DIM * DIM, b2 + 2 * DIM, 0);

    // pool
    k_starts<<<1, 128, 0, stream>>>(batch, starts);
    k_pool<<<NGRAPHS, 256, 0, stream>>>(hB, starts, out);
}

// Round 6
// 607.175 us; speedup vs baseline: 1.4306x; 1.3210x over previous
//
#include <hip/hip_runtime.h>
#include <float.h>

// PretrainingGIN on MI355X — Round 6.
// R5 post-mortem: gather is per-wave-concurrency bound (one row at a time per
// wave, full drain per node => <=2KB in flight); k_ell repeats the random-4B
// write-amplification (~105MB writeback).
// Changes:
//  - k_fused gather: 4 rows in parallel (16 lanes x dwordx4 per row), 8-deep
//    chunks => 8KB in flight per wave (4x), 4 drains instead of 16. Wave-max
//    loop bound via 2 shfl_xor; ELL rows zero-padded so loads never mask.
//  - Build: k_ell_t writes slot-striped ell_t[slot*N+dst] (dense stripes =>
//    full-line writebacks, ~10MB not 105MB), then k_tr LDS-transposes to
//    row-major ELL with zero padding (coalesced read AND write).

#define N_NODES 100000
#define N_EDGES 1600000
#define DIM 128
#define NGRAPHS 64
#define ELLW 64

#define BROWS 32           // rows per fused block (16 per wave, 2 waves)
#define LSTRIDE 136        // bf16 elems; 272B rows keep 16B align

typedef __attribute__((ext_vector_type(8))) short bf16x8;
typedef __attribute__((ext_vector_type(4))) float f32x4;

__device__ inline float bflo(unsigned u) { return __uint_as_float(u << 16); }
__device__ inline float bfhi(unsigned u) { return __uint_as_float(u & 0xffff0000u); }

__device__ inline unsigned short f2bf(float a) {      // RNE
    unsigned u = __float_as_uint(a);
    u = u + 0x7fff + ((u >> 16) & 1);
    return (unsigned short)(u >> 16);
}
__device__ inline unsigned f2bf_pack(float a, float b) {
    unsigned ua = __float_as_uint(a), ub = __float_as_uint(b);
    ua = ua + 0x7fff + ((ua >> 16) & 1);
    ub = ub + 0x7fff + ((ub >> 16) & 1);
    return (ua >> 16) | (ub & 0xffff0000u);
}

// ---------------- adjacency build (slot-striped, then transpose) ----------------
__global__ void k_zero_deg(int* __restrict__ deg) {
    int i = blockIdx.x * blockDim.x + threadIdx.x;
    if (i < N_NODES) deg[i] = 0;
}

// ell_t[slot][node]: stripes for slot < ~16 are densely written -> full-line
// writebacks instead of 64B-per-4B-store amplification.
__global__ void k_ell_t(const int* __restrict__ src, const int* __restrict__ dst,
                        int* __restrict__ deg, int* __restrict__ ell_t) {
    int e = blockIdx.x * blockDim.x + threadIdx.x;
    if (e < N_EDGES) {
        int d = dst[e];
        int slot = atomicAdd(&deg[d], 1);
        if (slot < ELLW) ell_t[(size_t)slot * N_NODES + d] = src[e];
    }
}

// 64x64 tiled transpose ell_t -> ell[node][slot], zero-padding slots >= deg.
__global__ __launch_bounds__(256) void k_tr(const int* __restrict__ ell_t,
                                            const int* __restrict__ deg,
                                            int* __restrict__ ell) {
    __shared__ int tile[ELLW][ELLW + 1];
    const int n0 = blockIdx.x * 64;
    const int t = threadIdx.x;
    {
        int ln = t & 63, sq = t >> 6;     // read coalesced along nodes
        int n = n0 + ln;
#pragma unroll
        for (int k = 0; k < 16; ++k) {
            int s = sq * 16 + k;
            tile[s][ln] = (n < N_NODES) ? ell_t[(size_t)s * N_NODES + n] : 0;
        }
    }
    __syncthreads();
    {
        int lr = t >> 2, c0 = (t & 3) * 16;   // write coalesced along slots
        int n = n0 + lr;
        if (n < N_NODES) {
            int dg = deg[n]; if (dg > ELLW) dg = ELLW;
            int* drow = ell + (size_t)n * ELLW + c0;
#pragma unroll
            for (int k4 = 0; k4 < 4; ++k4) {
                int4 w;
                int s = c0 + k4 * 4;
                w.x = (s + 0 < dg) ? tile[s + 0][lr] : 0;
                w.y = (s + 1 < dg) ? tile[s + 1][lr] : 0;
                w.z = (s + 2 < dg) ? tile[s + 2][lr] : 0;
                w.w = (s + 3 < dg) ? tile[s + 3][lr] : 0;
                *(int4*)(drow + k4 * 4) = w;
            }
        }
    }
}

// ---------------- dtype prep ----------------
__global__ void k_cast(const float* __restrict__ x, unsigned short* __restrict__ y) {
    int i = (blockIdx.x * blockDim.x + threadIdx.x) * 4;
    if (i < N_NODES * DIM) {
        float4 v = *(const float4*)(x + i);
        uint2 o;
        o.x = f2bf_pack(v.x, v.y);
        o.y = f2bf_pack(v.z, v.w);
        *(uint2*)(y + i) = o;
    }
}

// Repack W (k-major 128x128 fp32) into B-fragment order bf16:
// pack[mat][kb*4096 + c*32 + q*8 + j] = W[mat][(kb*32 + q*8 + j)*128 + c]
__global__ void k_pack(const float* __restrict__ W1, const float* __restrict__ W2,
                       unsigned short* __restrict__ pack) {
    int tid = blockIdx.x * blockDim.x + threadIdx.x;
    if (tid >= 6 * DIM * DIM) return;
    int mat = tid >> 14;
    int e = tid & 16383;
    int k = e >> 7, c = e & 127;
    const float* W = (mat < 3) ? (W1 + mat * DIM * DIM) : (W2 + (mat - 3) * DIM * DIM);
    int kb = k >> 5, q = (k >> 3) & 3, j = k & 7;
    pack[mat * DIM * DIM + kb * 4096 + c * 32 + q * 8 + j] = f2bf(W[k * DIM + c]);
}

// ---------------- fused layer: h_out = MLP(h + sum_{j->i} h_j) ----------------
// 2 waves/block, no barriers. Gather: wave splits into 4 x 16-lane groups;
// group g gathers row (j*4+g) via dwordx4 (16 lanes x 16B = 256B row), 8-deep
// chunks -> 8KB in flight per wave. ELL rows are zero-padded so all loads are
// address-safe; only values are masked.
__global__ __launch_bounds__(128) void k_fused(const unsigned short* __restrict__ h,
                                               const int* __restrict__ deg,
                                               const int* __restrict__ ell,
                                               unsigned short* __restrict__ hout,
                                               const unsigned short* __restrict__ Wp1,
                                               const float* __restrict__ b1,
                                               const unsigned short* __restrict__ Wp2,
                                               const float* __restrict__ b2,
                                               int relu_out) {
    __shared__ unsigned short buf[BROWS * LSTRIDE];   // 8704 B
    const int tid = threadIdx.x;
    const int wv = tid >> 6, lane = tid & 63;
    const int q = lane >> 4, n = lane & 15;
    const int sub = lane >> 4, ln16 = lane & 15;      // gather grouping
    const int row0 = blockIdx.x * BROWS;

    // ---- gather: 4 iterations x 4 parallel rows ----
#pragma unroll 1
    for (int j = 0; j < 4; ++j) {
        const int node = row0 + wv * 16 + j * 4 + sub;
        const unsigned short* hb = h + (size_t)node * DIM + ln16 * 8;
        uint4 sv = *(const uint4*)hb;                  // self row segment
        float a0 = bflo(sv.x), a1 = bfhi(sv.x);
        float a2 = bflo(sv.y), a3 = bfhi(sv.y);
        float a4 = bflo(sv.z), a5 = bfhi(sv.z);
        float a6 = bflo(sv.w), a7 = bfhi(sv.w);

        int dgv = deg[node];
        if (dgv > ELLW) dgv = ELLW;
        int m1 = max(dgv, __shfl_xor(dgv, 16));
        int mx = max(m1, __shfl_xor(m1, 32));          // wave-uniform bound
        const int* er = ell + (size_t)node * ELLW;

        for (int e = 0; e < mx; e += 8) {
            int4 iA = *(const int4*)(er + e);          // zero-padded: safe
            int4 iB = *(const int4*)(er + e + 4);
            uint4 r0 = *(const uint4*)(h + (size_t)iA.x * DIM + ln16 * 8);
            uint4 r1 = *(const uint4*)(h + (size_t)iA.y * DIM + ln16 * 8);
            uint4 r2 = *(const uint4*)(h + (size_t)iA.z * DIM + ln16 * 8);
            uint4 r3 = *(const uint4*)(h + (size_t)iA.w * DIM + ln16 * 8);
            uint4 r4 = *(const uint4*)(h + (size_t)iB.x * DIM + ln16 * 8);
            uint4 r5 = *(const uint4*)(h + (size_t)iB.y * DIM + ln16 * 8);
            uint4 r6 = *(const uint4*)(h + (size_t)iB.z * DIM + ln16 * 8);
            uint4 r7 = *(const uint4*)(h + (size_t)iB.w * DIM + ln16 * 8);
#define ACC(RK, K)                                                        \
            {                                                             \
                unsigned w0 = (e + (K) < dgv) ? RK.x : 0u;                \
                unsigned w1 = (e + (K) < dgv) ? RK.y : 0u;                \
                unsigned w2 = (e + (K) < dgv) ? RK.z : 0u;                \
                unsigned w3 = (e + (K) < dgv) ? RK.w : 0u;                \
                a0 += bflo(w0); a1 += bfhi(w0);                           \
                a2 += bflo(w1); a3 += bfhi(w1);                           \
                a4 += bflo(w2); a5 += bfhi(w2);                           \
                a6 += bflo(w3); a7 += bfhi(w3);                           \
            }
            ACC(r0, 0) ACC(r1, 1) ACC(r2, 2) ACC(r3, 3)
            ACC(r4, 4) ACC(r5, 5) ACC(r6, 6) ACC(r7, 7)
#undef ACC
        }

        uint4 o;
        o.x = f2bf_pack(a0, a1);
        o.y = f2bf_pack(a2, a3);
        o.z = f2bf_pack(a4, a5);
        o.w = f2bf_pack(a6, a7);
        *(uint4*)&buf[(wv * 16 + j * 4 + sub) * LSTRIDE + ln16 * 8] = o;
    }

    // ---- A1 fragments from own LDS rows (wave-private, no barrier) ----
    bf16x8 a1f[4];
    {
        const unsigned short* mr = buf + (wv * 16 + n) * LSTRIDE + q * 8;
#pragma unroll
        for (int kb = 0; kb < 4; ++kb) a1f[kb] = *(const bf16x8*)(mr + kb * 32);
    }

    float bia1[8], bia2[8];
#pragma unroll
    for (int ct = 0; ct < 8; ++ct) {
        bia1[ct] = b1[ct * 16 + n];
        bia2[ct] = b2[ct * 16 + n];
    }

    // ---- GEMM1: t = relu(m@W1 + b1), overwrite own LDS rows ----
#pragma unroll
    for (int ct = 0; ct < 8; ++ct) {
        f32x4 acc = {0.f, 0.f, 0.f, 0.f};
#pragma unroll
        for (int kb = 0; kb < 4; ++kb) {
            bf16x8 b = *(const bf16x8*)(Wp1 + kb * 4096 + (ct * 16 + n) * 32 + q * 8);
            acc = __builtin_amdgcn_mfma_f32_16x16x32_bf16(a1f[kb], b, acc, 0, 0, 0);
        }
#pragma unroll
        for (int r = 0; r < 4; ++r)
            buf[(wv * 16 + q * 4 + r) * LSTRIDE + ct * 16 + n] =
                f2bf(fmaxf(acc[r] + bia1[ct], 0.f));
    }

    // ---- A2 fragments ----
    bf16x8 a2f[4];
    {
        const unsigned short* tr = buf + (wv * 16 + n) * LSTRIDE + q * 8;
#pragma unroll
        for (int kb = 0; kb < 4; ++kb) a2f[kb] = *(const bf16x8*)(tr + kb * 32);
    }

    // ---- GEMM2: out = t@W2 + b2, overwrite own LDS rows ----
#pragma unroll
    for (int ct = 0; ct < 8; ++ct) {
        f32x4 acc = {0.f, 0.f, 0.f, 0.f};
#pragma unroll
        for (int kb = 0; kb < 4; ++kb) {
            bf16x8 b = *(const bf16x8*)(Wp2 + kb * 4096 + (ct * 16 + n) * 32 + q * 8);
            acc = __builtin_amdgcn_mfma_f32_16x16x32_bf16(a2f[kb], b, acc, 0, 0, 0);
        }
#pragma unroll
        for (int r = 0; r < 4; ++r) {
            float v = acc[r] + bia2[ct];
            if (relu_out) v = fmaxf(v, 0.f);
            buf[(wv * 16 + q * 4 + r) * LSTRIDE + ct * 16 + n] = f2bf(v);
        }
    }

    // ---- store own wave's 16 rows, coalesced (no barrier needed) ----
    {
#pragma unroll
        for (int s = 0; s < 4; ++s) {
            int lr = wv * 16 + s * 4 + (lane >> 4);
            int c0 = (lane & 15) * 8;
            *(bf16x8*)(hout + (size_t)(row0 + lr) * DIM + c0) =
                *(const bf16x8*)(buf + lr * LSTRIDE + c0);
        }
    }
}

// ---------------- pool ----------------
__global__ void k_starts(const int* __restrict__ batch, int* __restrict__ starts) {
    int g = threadIdx.x;
    if (g > NGRAPHS) return;
    int lo = 0, hi = N_NODES;
    while (lo < hi) {
        int mid = (lo + hi) >> 1;
        if (batch[mid] < g) lo = mid + 1;
        else hi = mid;
    }
    starts[g] = lo;
}

__global__ __launch_bounds__(256) void k_pool(const unsigned short* __restrict__ h,
                                              const int* __restrict__ starts,
                                              float* __restrict__ out) {
    __shared__ float red[4][DIM];
    int g = blockIdx.x;
    int t = threadIdx.x;
    int rowpar = t >> 6;
    int col = (t & 63) * 2;
    int i0 = starts[g], i1 = starts[g + 1];
    float mx = -FLT_MAX, my = -FLT_MAX;
    for (int i = i0 + rowpar; i < i1; i += 4) {
        unsigned u = *(const unsigned*)(h + (size_t)i * DIM + col);
        mx = fmaxf(mx, bflo(u));
        my = fmaxf(my, bfhi(u));
    }
    red[rowpar][col] = mx;
    red[rowpar][col + 1] = my;
    __syncthreads();
    if (rowpar == 0) {
        mx = fmaxf(fmaxf(red[0][col], red[1][col]), fmaxf(red[2][col], red[3][col]));
        my = fmaxf(fmaxf(red[0][col + 1], red[1][col + 1]),
                   fmaxf(red[2][col + 1], red[3][col + 1]));
        out[g * DIM + col] = mx;
        out[g * DIM + col + 1] = my;
    }
}

extern "C" void kernel_launch(void* const* d_in, const int* in_sizes, int n_in,
                              void* d_out, int out_size, void* d_ws, size_t ws_size,
                              hipStream_t stream) {
    const float* x   = (const float*)d_in[0];
    const int* ei    = (const int*)d_in[1];
    const int* batch = (const int*)d_in[2];
    const float* W1  = (const float*)d_in[3];
    const float* b1  = (const float*)d_in[4];
    const float* W2  = (const float*)d_in[5];
    const float* b2  = (const float*)d_in[6];
    float* out = (float*)d_out;

    const int* src = ei;
    const int* dst = ei + N_EDGES;

    unsigned short* hA  = (unsigned short*)d_ws;                  // 25.6 MB
    unsigned short* hB  = hA + (size_t)N_NODES * DIM;             // 25.6 MB
    int* ell            = (int*)(hB + (size_t)N_NODES * DIM);     // 25.6 MB
    int* ell_t          = ell + (size_t)N_NODES * ELLW;           // 25.6 MB
    int* deg            = ell_t + (size_t)N_NODES * ELLW;         // 400 KB
    unsigned short* wpk = (unsigned short*)(deg + N_NODES);       // 192 KB
    int* starts         = (int*)(wpk + 6 * DIM * DIM);            // 65

    // adjacency build
    k_zero_deg<<<(N_NODES + 255) / 256, 256, 0, stream>>>(deg);
    k_ell_t<<<(N_EDGES + 255) / 256, 256, 0, stream>>>(src, dst, deg, ell_t);
    k_tr<<<(N_NODES + 63) / 64, 256, 0, stream>>>(ell_t, deg, ell);

    // dtype prep
    k_cast<<<(N_NODES * DIM / 4 + 255) / 256, 256, 0, stream>>>(x, hA);
    k_pack<<<(6 * DIM * DIM + 255) / 256, 256, 0, stream>>>(W1, W2, wpk);

    const int fusedBlocks = N_NODES / BROWS;   // 3125 exactly
    unsigned short* Wp1 = wpk;
    unsigned short* Wp2 = wpk + 3 * DIM * DIM;

    // 3 fused layers, ping-pong hA <-> hB
    k_fused<<<fusedBlocks, 128, 0, stream>>>(hA, deg, ell, hB,
                                             Wp1, b1, Wp2, b2, 1);
    k_fused<<<fusedBlocks, 128, 0, stream>>>(hB, deg, ell, hA,
                                             Wp1 + DIM * DIM, b1 + DIM,
                                             Wp2 + DIM * DIM, b2 + DIM, 1);
    k_fused<<<fusedBlocks, 128, 0, stream>>>(hA, deg, ell, hB,
                                             Wp1 + 2 * DIM * DIM, b1 + 2 * DIM,
                                             Wp2 + 2 * DIM * DIM, b2 + 2 * DIM, 0);

    // pool
    k_starts<<<1, 128, 0, stream>>>(batch, starts);
    k_pool<<<NGRAPHS, 256, 0, stream>>>(hB, starts, out);
}

// Round 7
// 501.458 us; speedup vs baseline: 1.7322x; 1.2108x over previous
//
#include <hip/hip_runtime.h>
#include <float.h>

// PretrainingGIN on MI355X — Round 7.
// R6 post-mortem: k_ell_t still 122us/105MB — random 4B stores over 25.6MB
// have no TEMPORAL locality regardless of stripe layout. Fix: 2-pass bucketed
// build (block-local LDS binning -> contiguous per-block runs; then per-bucket
// CSR fill inside a 20KB L2-resident window). Gather: wave's CSR rows are
// contiguous -> cooperative index staging into LDS kills the dependent
// index-load chain.

#define N_NODES 100000
#define N_EDGES 1600000
#define DIM 128
#define NGRAPHS 64

#define NBUCK 391          // ceil(100000/256) buckets of 256 nodes
#define BCAP 5120          // max edges/bucket (mean 4096, +16 sigma)
#define CCAP 6144          // ssrc ints per bucket (edges + per-node align pad)
#define EPT 8              // edges per thread in k_bucket
#define EPB 2048           // 256*8 edges per block

#define BROWS 32           // rows per fused block (16 per wave, 2 waves)
#define LSTRIDE 136        // bf16 elems; 272B rows keep 16B align
#define IDXCAP 1024        // staged indices per wave (16 nodes * <=64)

typedef __attribute__((ext_vector_type(8))) short bf16x8;
typedef __attribute__((ext_vector_type(4))) float f32x4;

__device__ inline float bflo(unsigned u) { return __uint_as_float(u << 16); }
__device__ inline float bfhi(unsigned u) { return __uint_as_float(u & 0xffff0000u); }

__device__ inline unsigned short f2bf(float a) {      // RNE
    unsigned u = __float_as_uint(a);
    u = u + 0x7fff + ((u >> 16) & 1);
    return (unsigned short)(u >> 16);
}
__device__ inline unsigned f2bf_pack(float a, float b) {
    unsigned ua = __float_as_uint(a), ub = __float_as_uint(b);
    ua = ua + 0x7fff + ((ua >> 16) & 1);
    ub = ub + 0x7fff + ((ub >> 16) & 1);
    return (ua >> 16) | (ub & 0xffff0000u);
}

// ---------------- build pass A: bucket the edges ----------------
__global__ void k_zero_gcnt(int* __restrict__ gcnt) {
    int i = blockIdx.x * blockDim.x + threadIdx.x;
    if (i < NBUCK) gcnt[i] = 0;
}

// Block bins 2048 edges into 391 buckets via LDS histogram; reserves global
// per-bucket ranges (1 atomic per bucket per block); writes packed
// (dstLocal<<17|src) into contiguous per-block runs.
__global__ __launch_bounds__(256) void k_bucket(const int* __restrict__ src,
                                                const int* __restrict__ dst,
                                                int* __restrict__ gcnt,
                                                unsigned* __restrict__ store) {
    __shared__ int hist[NBUCK];
    __shared__ int base[NBUCK];
    const int t = threadIdx.x;
    const int e0 = blockIdx.x * EPB;

    for (int i = t; i < NBUCK; i += 256) hist[i] = 0;
    __syncthreads();

    int bk[EPT], rk[EPT];
    unsigned pk[EPT];
#pragma unroll
    for (int k = 0; k < EPT; ++k) {
        int e = e0 + k * 256 + t;
        bk[k] = -1;
        if (e < N_EDGES) {
            int d = dst[e];
            int s = src[e];
            int b = d >> 8;
            bk[k] = b;
            rk[k] = atomicAdd(&hist[b], 1);
            pk[k] = ((unsigned)(d & 255) << 17) | (unsigned)s;
        }
    }
    __syncthreads();
    for (int i = t; i < NBUCK; i += 256)
        if (hist[i] > 0) base[i] = atomicAdd(&gcnt[i], hist[i]);
    __syncthreads();
#pragma unroll
    for (int k = 0; k < EPT; ++k) {
        if (bk[k] >= 0) {
            int p = base[bk[k]] + rk[k];
            if (p < BCAP) store[(size_t)bk[k] * BCAP + p] = pk[k];
        }
    }
}

// ---------------- build pass B: per-bucket CSR fill ----------------
// Block = bucket (256 nodes). Local histogram + LDS scan -> 16B-aligned node
// offsets; scatter srcs inside the bucket's ~20KB window (L2-local).
__global__ __launch_bounds__(256) void k_csr(const unsigned* __restrict__ store,
                                             const int* __restrict__ gcnt,
                                             int* __restrict__ offs,
                                             int* __restrict__ deg,
                                             int* __restrict__ ssrc) {
    __shared__ int hist[256];
    __shared__ int s[256];
    __shared__ int pos[256];
    const int b = blockIdx.x;
    const int t = threadIdx.x;
    int nE = gcnt[b];
    if (nE > BCAP) nE = BCAP;

    hist[t] = 0;
    __syncthreads();
    const unsigned* bs = store + (size_t)b * BCAP;
    for (int e = t; e < nE; e += 256)
        atomicAdd(&hist[bs[e] >> 17], 1);
    __syncthreads();

    int cnt = hist[t];
    int al = (cnt + 3) & ~3;          // 16B-align each node's segment
    s[t] = al;
    __syncthreads();
    for (int off = 1; off < 256; off <<= 1) {
        int x = (t >= off) ? s[t - off] : 0;
        __syncthreads();
        s[t] += x;
        __syncthreads();
    }
    int loc = s[t] - al;              // exclusive prefix
    int node = b * 256 + t;
    if (node < N_NODES) {
        offs[node] = b * CCAP + loc;
        deg[node] = cnt;
    }
    pos[t] = loc;
    __syncthreads();

    int* out = ssrc + (size_t)b * CCAP;
    for (int e = t; e < nE; e += 256) {
        unsigned p = bs[e];
        int dl = p >> 17;
        int q = atomicAdd(&pos[dl], 1);
        out[q] = (int)(p & 0x1FFFFu);
    }
}

// ---------------- dtype prep ----------------
__global__ void k_cast(const float* __restrict__ x, unsigned short* __restrict__ y) {
    int i = (blockIdx.x * blockDim.x + threadIdx.x) * 4;
    if (i < N_NODES * DIM) {
        float4 v = *(const float4*)(x + i);
        uint2 o;
        o.x = f2bf_pack(v.x, v.y);
        o.y = f2bf_pack(v.z, v.w);
        *(uint2*)(y + i) = o;
    }
}

// Repack W (k-major 128x128 fp32) into B-fragment order bf16:
// pack[mat][kb*4096 + c*32 + q*8 + j] = W[mat][(kb*32 + q*8 + j)*128 + c]
__global__ void k_pack(const float* __restrict__ W1, const float* __restrict__ W2,
                       unsigned short* __restrict__ pack) {
    int tid = blockIdx.x * blockDim.x + threadIdx.x;
    if (tid >= 6 * DIM * DIM) return;
    int mat = tid >> 14;
    int e = tid & 16383;
    int k = e >> 7, c = e & 127;
    const float* W = (mat < 3) ? (W1 + mat * DIM * DIM) : (W2 + (mat - 3) * DIM * DIM);
    int kb = k >> 5, q = (k >> 3) & 3, j = k & 7;
    pack[mat * DIM * DIM + kb * 4096 + c * 32 + q * 8 + j] = f2bf(W[k * DIM + c]);
}

// ---------------- fused layer: h_out = MLP(h + sum_{j->i} h_j) ----------------
// 2 waves/block, no barriers. Wave stages all its ~280 CSR indices into LDS
// (contiguous rows!), then gathers 4 rows in parallel (16 lanes x dwordx4),
// 8-deep, with indices from LDS (broadcast) — no dependent VMEM index chain.
__global__ __launch_bounds__(128) void k_fused(const unsigned short* __restrict__ h,
                                               const int* __restrict__ offs,
                                               const int* __restrict__ deg,
                                               const int* __restrict__ ssrc,
                                               unsigned short* __restrict__ hout,
                                               const unsigned short* __restrict__ Wp1,
                                               const float* __restrict__ b1,
                                               const unsigned short* __restrict__ Wp2,
                                               const float* __restrict__ b2,
                                               int relu_out) {
    __shared__ int idx[2][IDXCAP];                    // 8192 B
    __shared__ unsigned short buf[BROWS * LSTRIDE];   // 8704 B
    const int tid = threadIdx.x;
    const int wv = tid >> 6, lane = tid & 63;
    const int q = lane >> 4, n = lane & 15;
    const int sub = lane >> 4, ln16 = lane & 15;
    const int row0 = blockIdx.x * BROWS;
    const int nb0 = row0 + wv * 16;                   // wave's first node

    // ---- stage the wave's indices (contiguous CSR range) into LDS ----
    const int base0 = offs[nb0];
    int cnt = offs[nb0 + 15] + deg[nb0 + 15] - base0; // rows are contiguous
    if (cnt > IDXCAP) cnt = IDXCAP;
    for (int i = lane * 4; i < cnt; i += 256) {       // base0 is 16B aligned
        int4 v = *(const int4*)(ssrc + base0 + i);
        *(int4*)&idx[wv][i] = v;
    }

    // ---- gather: 4 iterations x 4 parallel rows ----
#pragma unroll 1
    for (int j = 0; j < 4; ++j) {
        const int node = nb0 + j * 4 + sub;
        const unsigned short* hb = h + (size_t)node * DIM + ln16 * 8;
        uint4 sv = *(const uint4*)hb;                 // self row segment
        float a0 = bflo(sv.x), a1 = bfhi(sv.x);
        float a2 = bflo(sv.y), a3 = bfhi(sv.y);
        float a4 = bflo(sv.z), a5 = bfhi(sv.z);
        float a6 = bflo(sv.w), a7 = bfhi(sv.w);

        const int loc = offs[node] - base0;           // 4-aligned
        const int dgv = deg[node];
        int m1 = max(dgv, __shfl_xor(dgv, 16));
        int mx = max(m1, __shfl_xor(m1, 32));         // wave-uniform bound

        for (int e = 0; e < mx; e += 8) {
            int4 iA = *(const int4*)&idx[wv][loc + e];      // ds_read_b128,
            int4 iB = *(const int4*)&idx[wv][loc + e + 4];  // 16-lane broadcast
            int s0 = min(iA.x & 0x1FFFF, N_NODES - 1);
            int s1 = min(iA.y & 0x1FFFF, N_NODES - 1);
            int s2 = min(iA.z & 0x1FFFF, N_NODES - 1);
            int s3 = min(iA.w & 0x1FFFF, N_NODES - 1);
            int s4 = min(iB.x & 0x1FFFF, N_NODES - 1);
            int s5 = min(iB.y & 0x1FFFF, N_NODES - 1);
            int s6 = min(iB.z & 0x1FFFF, N_NODES - 1);
            int s7 = min(iB.w & 0x1FFFF, N_NODES - 1);
            uint4 r0 = *(const uint4*)(h + (size_t)s0 * DIM + ln16 * 8);
            uint4 r1 = *(const uint4*)(h + (size_t)s1 * DIM + ln16 * 8);
            uint4 r2 = *(const uint4*)(h + (size_t)s2 * DIM + ln16 * 8);
            uint4 r3 = *(const uint4*)(h + (size_t)s3 * DIM + ln16 * 8);
            uint4 r4 = *(const uint4*)(h + (size_t)s4 * DIM + ln16 * 8);
            uint4 r5 = *(const uint4*)(h + (size_t)s5 * DIM + ln16 * 8);
            uint4 r6 = *(const uint4*)(h + (size_t)s6 * DIM + ln16 * 8);
            uint4 r7 = *(const uint4*)(h + (size_t)s7 * DIM + ln16 * 8);
#define ACC(RK, K)                                                        \
            {                                                             \
                unsigned w0 = (e + (K) < dgv) ? RK.x : 0u;                \
                unsigned w1 = (e + (K) < dgv) ? RK.y : 0u;                \
                unsigned w2 = (e + (K) < dgv) ? RK.z : 0u;                \
                unsigned w3 = (e + (K) < dgv) ? RK.w : 0u;                \
                a0 += bflo(w0); a1 += bfhi(w0);                           \
                a2 += bflo(w1); a3 += bfhi(w1);                           \
                a4 += bflo(w2); a5 += bfhi(w2);                           \
                a6 += bflo(w3); a7 += bfhi(w3);                           \
            }
            ACC(r0, 0) ACC(r1, 1) ACC(r2, 2) ACC(r3, 3)
            ACC(r4, 4) ACC(r5, 5) ACC(r6, 6) ACC(r7, 7)
#undef ACC
        }

        uint4 o;
        o.x = f2bf_pack(a0, a1);
        o.y = f2bf_pack(a2, a3);
        o.z = f2bf_pack(a4, a5);
        o.w = f2bf_pack(a6, a7);
        *(uint4*)&buf[(wv * 16 + j * 4 + sub) * LSTRIDE + ln16 * 8] = o;
    }

    // ---- A1 fragments from own LDS rows (wave-private, no barrier) ----
    bf16x8 a1f[4];
    {
        const unsigned short* mr = buf + (wv * 16 + n) * LSTRIDE + q * 8;
#pragma unroll
        for (int kb = 0; kb < 4; ++kb) a1f[kb] = *(const bf16x8*)(mr + kb * 32);
    }

    float bia1[8], bia2[8];
#pragma unroll
    for (int ct = 0; ct < 8; ++ct) {
        bia1[ct] = b1[ct * 16 + n];
        bia2[ct] = b2[ct * 16 + n];
    }

    // ---- GEMM1: t = relu(m@W1 + b1), overwrite own LDS rows ----
#pragma unroll
    for (int ct = 0; ct < 8; ++ct) {
        f32x4 acc = {0.f, 0.f, 0.f, 0.f};
#pragma unroll
        for (int kb = 0; kb < 4; ++kb) {
            bf16x8 b = *(const bf16x8*)(Wp1 + kb * 4096 + (ct * 16 + n) * 32 + q * 8);
            acc = __builtin_amdgcn_mfma_f32_16x16x32_bf16(a1f[kb], b, acc, 0, 0, 0);
        }
#pragma unroll
        for (int r = 0; r < 4; ++r)
            buf[(wv * 16 + q * 4 + r) * LSTRIDE + ct * 16 + n] =
                f2bf(fmaxf(acc[r] + bia1[ct], 0.f));
    }

    // ---- A2 fragments ----
    bf16x8 a2f[4];
    {
        const unsigned short* tr = buf + (wv * 16 + n) * LSTRIDE + q * 8;
#pragma unroll
        for (int kb = 0; kb < 4; ++kb) a2f[kb] = *(const bf16x8*)(tr + kb * 32);
    }

    // ---- GEMM2: out = t@W2 + b2, overwrite own LDS rows ----
#pragma unroll
    for (int ct = 0; ct < 8; ++ct) {
        f32x4 acc = {0.f, 0.f, 0.f, 0.f};
#pragma unroll
        for (int kb = 0; kb < 4; ++kb) {
            bf16x8 b = *(const bf16x8*)(Wp2 + kb * 4096 + (ct * 16 + n) * 32 + q * 8);
            acc = __builtin_amdgcn_mfma_f32_16x16x32_bf16(a2f[kb], b, acc, 0, 0, 0);
        }
#pragma unroll
        for (int r = 0; r < 4; ++r) {
            float v = acc[r] + bia2[ct];
            if (relu_out) v = fmaxf(v, 0.f);
            buf[(wv * 16 + q * 4 + r) * LSTRIDE + ct * 16 + n] = f2bf(v);
        }
    }

    // ---- store own wave's 16 rows, coalesced (no barrier needed) ----
    {
#pragma unroll
        for (int s2 = 0; s2 < 4; ++s2) {
            int lr = wv * 16 + s2 * 4 + (lane >> 4);
            int c0 = (lane & 15) * 8;
            *(bf16x8*)(hout + (size_t)(row0 + lr) * DIM + c0) =
                *(const bf16x8*)(buf + lr * LSTRIDE + c0);
        }
    }
}

// ---------------- pool ----------------
__global__ void k_starts(const int* __restrict__ batch, int* __restrict__ starts) {
    int g = threadIdx.x;
    if (g > NGRAPHS) return;
    int lo = 0, hi = N_NODES;
    while (lo < hi) {
        int mid = (lo + hi) >> 1;
        if (batch[mid] < g) lo = mid + 1;
        else hi = mid;
    }
    starts[g] = lo;
}

__global__ __launch_bounds__(256) void k_pool(const unsigned short* __restrict__ h,
                                              const int* __restrict__ starts,
                                              float* __restrict__ out) {
    __shared__ float red[4][DIM];
    int g = blockIdx.x;
    int t = threadIdx.x;
    int rowpar = t >> 6;
    int col = (t & 63) * 2;
    int i0 = starts[g], i1 = starts[g + 1];
    float mx = -FLT_MAX, my = -FLT_MAX;
    for (int i = i0 + rowpar; i < i1; i += 4) {
        unsigned u = *(const unsigned*)(h + (size_t)i * DIM + col);
        mx = fmaxf(mx, bflo(u));
        my = fmaxf(my, bfhi(u));
    }
    red[rowpar][col] = mx;
    red[rowpar][col + 1] = my;
    __syncthreads();
    if (rowpar == 0) {
        mx = fmaxf(fmaxf(red[0][col], red[1][col]), fmaxf(red[2][col], red[3][col]));
        my = fmaxf(fmaxf(red[0][col + 1], red[1][col + 1]),
                   fmaxf(red[2][col + 1], red[3][col + 1]));
        out[g * DIM + col] = mx;
        out[g * DIM + col + 1] = my;
    }
}

extern "C" void kernel_launch(void* const* d_in, const int* in_sizes, int n_in,
                              void* d_out, int out_size, void* d_ws, size_t ws_size,
                              hipStream_t stream) {
    const float* x   = (const float*)d_in[0];
    const int* ei    = (const int*)d_in[1];
    const int* batch = (const int*)d_in[2];
    const float* W1  = (const float*)d_in[3];
    const float* b1  = (const float*)d_in[4];
    const float* W2  = (const float*)d_in[5];
    const float* b2  = (const float*)d_in[6];
    float* out = (float*)d_out;

    const int* src = ei;
    const int* dst = ei + N_EDGES;

    unsigned short* hA  = (unsigned short*)d_ws;                   // 25.6 MB
    unsigned short* hB  = hA + (size_t)N_NODES * DIM;              // 25.6 MB
    unsigned* store     = (unsigned*)(hB + (size_t)N_NODES * DIM); // 8.0 MB
    int* ssrc           = (int*)(store + (size_t)NBUCK * BCAP);    // 9.6 MB
    int* offs           = ssrc + (size_t)NBUCK * CCAP + 64;        // 400 KB
    int* deg            = offs + N_NODES;                          // 400 KB
    int* gcnt           = deg + N_NODES;                           // NBUCK
    unsigned short* wpk = (unsigned short*)(gcnt + NBUCK);         // 192 KB
    int* starts         = (int*)(wpk + 6 * DIM * DIM);             // 65

    // bucketed CSR build
    k_zero_gcnt<<<2, 256, 0, stream>>>(gcnt);
    k_bucket<<<(N_EDGES + EPB - 1) / EPB, 256, 0, stream>>>(src, dst, gcnt, store);
    k_csr<<<NBUCK, 256, 0, stream>>>(store, gcnt, offs, deg, ssrc);

    // dtype prep
    k_cast<<<(N_NODES * DIM / 4 + 255) / 256, 256, 0, stream>>>(x, hA);
    k_pack<<<(6 * DIM * DIM + 255) / 256, 256, 0, stream>>>(W1, W2, wpk);

    const int fusedBlocks = N_NODES / BROWS;   // 3125 exactly
    unsigned short* Wp1 = wpk;
    unsigned short* Wp2 = wpk + 3 * DIM * DIM;

    // 3 fused layers, ping-pong hA <-> hB
    k_fused<<<fusedBlocks, 128, 0, stream>>>(hA, offs, deg, ssrc, hB,
                                             Wp1, b1, Wp2, b2, 1);
    k_fused<<<fusedBlocks, 128, 0, stream>>>(hB, offs, deg, ssrc, hA,
                                             Wp1 + DIM * DIM, b1 + DIM,
                                             Wp2 + DIM * DIM, b2 + DIM, 1);
    k_fused<<<fusedBlocks, 128, 0, stream>>>(hA, offs, deg, ssrc, hB,
                                             Wp1 + 2 * DIM * DIM, b1 + 2 * DIM,
                                             Wp2 + 2 * DIM * DIM, b2 + 2 * DIM, 0);

    // pool
    k_starts<<<1, 128, 0, stream>>>(batch, starts);
    k_pool<<<NGRAPHS, 256, 0, stream>>>(hB, starts, out);
}

// Round 8
// 402.600 us; speedup vs baseline: 2.1576x; 1.2455x over previous
//
#include <hip/hip_runtime.h>
#include <float.h>

// PretrainingGIN on MI355X — Round 8.
// R7 post-mortem: k_pool was latency-starved (64 blocks = 1 wave/CU, 115us
// for 12.8MB @ 111GB/s, 2.5% occupancy). Replaced with a two-stage pool:
// stage1 = 1024 blocks (16 chunks/graph) -> 512KB partials; stage2 folds.
// Build (bucketed CSR), fused agg+MLP (bf16 MFMA, barrier-free), unchanged.

#define N_NODES 100000
#define N_EDGES 1600000
#define DIM 128
#define NGRAPHS 64
#define PCHUNK 16          // pool stage-1 chunks per graph

#define NBUCK 391          // ceil(100000/256) buckets of 256 nodes
#define BCAP 5120          // max edges/bucket (mean 4096, +16 sigma)
#define CCAP 6144          // ssrc ints per bucket (edges + per-node align pad)
#define EPT 8              // edges per thread in k_bucket
#define EPB 2048           // 256*8 edges per block

#define BROWS 32           // rows per fused block (16 per wave, 2 waves)
#define LSTRIDE 136        // bf16 elems; 272B rows keep 16B align
#define IDXCAP 1024        // staged indices per wave (16 nodes * <=64)

typedef __attribute__((ext_vector_type(8))) short bf16x8;
typedef __attribute__((ext_vector_type(4))) float f32x4;

__device__ inline float bflo(unsigned u) { return __uint_as_float(u << 16); }
__device__ inline float bfhi(unsigned u) { return __uint_as_float(u & 0xffff0000u); }

__device__ inline unsigned short f2bf(float a) {      // RNE
    unsigned u = __float_as_uint(a);
    u = u + 0x7fff + ((u >> 16) & 1);
    return (unsigned short)(u >> 16);
}
__device__ inline unsigned f2bf_pack(float a, float b) {
    unsigned ua = __float_as_uint(a), ub = __float_as_uint(b);
    ua = ua + 0x7fff + ((ua >> 16) & 1);
    ub = ub + 0x7fff + ((ub >> 16) & 1);
    return (ua >> 16) | (ub & 0xffff0000u);
}

// ---------------- build pass A: bucket the edges ----------------
__global__ void k_zero_gcnt(int* __restrict__ gcnt) {
    int i = blockIdx.x * blockDim.x + threadIdx.x;
    if (i < NBUCK) gcnt[i] = 0;
}

__global__ __launch_bounds__(256) void k_bucket(const int* __restrict__ src,
                                                const int* __restrict__ dst,
                                                int* __restrict__ gcnt,
                                                unsigned* __restrict__ store) {
    __shared__ int hist[NBUCK];
    __shared__ int base[NBUCK];
    const int t = threadIdx.x;
    const int e0 = blockIdx.x * EPB;

    for (int i = t; i < NBUCK; i += 256) hist[i] = 0;
    __syncthreads();

    int bk[EPT], rk[EPT];
    unsigned pk[EPT];
#pragma unroll
    for (int k = 0; k < EPT; ++k) {
        int e = e0 + k * 256 + t;
        bk[k] = -1;
        if (e < N_EDGES) {
            int d = dst[e];
            int s = src[e];
            int b = d >> 8;
            bk[k] = b;
            rk[k] = atomicAdd(&hist[b], 1);
            pk[k] = ((unsigned)(d & 255) << 17) | (unsigned)s;
        }
    }
    __syncthreads();
    for (int i = t; i < NBUCK; i += 256)
        if (hist[i] > 0) base[i] = atomicAdd(&gcnt[i], hist[i]);
    __syncthreads();
#pragma unroll
    for (int k = 0; k < EPT; ++k) {
        if (bk[k] >= 0) {
            int p = base[bk[k]] + rk[k];
            if (p < BCAP) store[(size_t)bk[k] * BCAP + p] = pk[k];
        }
    }
}

// ---------------- build pass B: per-bucket CSR fill ----------------
__global__ __launch_bounds__(256) void k_csr(const unsigned* __restrict__ store,
                                             const int* __restrict__ gcnt,
                                             int* __restrict__ offs,
                                             int* __restrict__ deg,
                                             int* __restrict__ ssrc) {
    __shared__ int hist[256];
    __shared__ int s[256];
    __shared__ int pos[256];
    const int b = blockIdx.x;
    const int t = threadIdx.x;
    int nE = gcnt[b];
    if (nE > BCAP) nE = BCAP;

    hist[t] = 0;
    __syncthreads();
    const unsigned* bs = store + (size_t)b * BCAP;
    for (int e = t; e < nE; e += 256)
        atomicAdd(&hist[bs[e] >> 17], 1);
    __syncthreads();

    int cnt = hist[t];
    int al = (cnt + 3) & ~3;          // 16B-align each node's segment
    s[t] = al;
    __syncthreads();
    for (int off = 1; off < 256; off <<= 1) {
        int x = (t >= off) ? s[t - off] : 0;
        __syncthreads();
        s[t] += x;
        __syncthreads();
    }
    int loc = s[t] - al;              // exclusive prefix
    int node = b * 256 + t;
    if (node < N_NODES) {
        offs[node] = b * CCAP + loc;
        deg[node] = cnt;
    }
    pos[t] = loc;
    __syncthreads();

    int* out = ssrc + (size_t)b * CCAP;
    for (int e = t; e < nE; e += 256) {
        unsigned p = bs[e];
        int dl = p >> 17;
        int q = atomicAdd(&pos[dl], 1);
        out[q] = (int)(p & 0x1FFFFu);
    }
}

// ---------------- dtype prep ----------------
__global__ void k_cast(const float* __restrict__ x, unsigned short* __restrict__ y) {
    int i = (blockIdx.x * blockDim.x + threadIdx.x) * 4;
    if (i < N_NODES * DIM) {
        float4 v = *(const float4*)(x + i);
        uint2 o;
        o.x = f2bf_pack(v.x, v.y);
        o.y = f2bf_pack(v.z, v.w);
        *(uint2*)(y + i) = o;
    }
}

__global__ void k_pack(const float* __restrict__ W1, const float* __restrict__ W2,
                       unsigned short* __restrict__ pack) {
    int tid = blockIdx.x * blockDim.x + threadIdx.x;
    if (tid >= 6 * DIM * DIM) return;
    int mat = tid >> 14;
    int e = tid & 16383;
    int k = e >> 7, c = e & 127;
    const float* W = (mat < 3) ? (W1 + mat * DIM * DIM) : (W2 + (mat - 3) * DIM * DIM);
    int kb = k >> 5, q = (k >> 3) & 3, j = k & 7;
    pack[mat * DIM * DIM + kb * 4096 + c * 32 + q * 8 + j] = f2bf(W[k * DIM + c]);
}

// ---------------- fused layer: h_out = MLP(h + sum_{j->i} h_j) ----------------
__global__ __launch_bounds__(128) void k_fused(const unsigned short* __restrict__ h,
                                               const int* __restrict__ offs,
                                               const int* __restrict__ deg,
                                               const int* __restrict__ ssrc,
                                               unsigned short* __restrict__ hout,
                                               const unsigned short* __restrict__ Wp1,
                                               const float* __restrict__ b1,
                                               const unsigned short* __restrict__ Wp2,
                                               const float* __restrict__ b2,
                                               int relu_out) {
    __shared__ int idx[2][IDXCAP];                    // 8192 B
    __shared__ unsigned short buf[BROWS * LSTRIDE];   // 8704 B
    const int tid = threadIdx.x;
    const int wv = tid >> 6, lane = tid & 63;
    const int q = lane >> 4, n = lane & 15;
    const int sub = lane >> 4, ln16 = lane & 15;
    const int row0 = blockIdx.x * BROWS;
    const int nb0 = row0 + wv * 16;                   // wave's first node

    // ---- stage the wave's indices (contiguous CSR range) into LDS ----
    const int base0 = offs[nb0];
    int cnt = offs[nb0 + 15] + deg[nb0 + 15] - base0;
    if (cnt > IDXCAP) cnt = IDXCAP;
    for (int i = lane * 4; i < cnt; i += 256) {
        int4 v = *(const int4*)(ssrc + base0 + i);
        *(int4*)&idx[wv][i] = v;
    }

    // ---- gather: 4 iterations x 4 parallel rows ----
#pragma unroll 1
    for (int j = 0; j < 4; ++j) {
        const int node = nb0 + j * 4 + sub;
        const unsigned short* hb = h + (size_t)node * DIM + ln16 * 8;
        uint4 sv = *(const uint4*)hb;
        float a0 = bflo(sv.x), a1 = bfhi(sv.x);
        float a2 = bflo(sv.y), a3 = bfhi(sv.y);
        float a4 = bflo(sv.z), a5 = bfhi(sv.z);
        float a6 = bflo(sv.w), a7 = bfhi(sv.w);

        const int loc = offs[node] - base0;
        const int dgv = deg[node];
        int m1 = max(dgv, __shfl_xor(dgv, 16));
        int mx = max(m1, __shfl_xor(m1, 32));

        for (int e = 0; e < mx; e += 8) {
            int4 iA = *(const int4*)&idx[wv][loc + e];
            int4 iB = *(const int4*)&idx[wv][loc + e + 4];
            int s0 = min(iA.x & 0x1FFFF, N_NODES - 1);
            int s1 = min(iA.y & 0x1FFFF, N_NODES - 1);
            int s2 = min(iA.z & 0x1FFFF, N_NODES - 1);
            int s3 = min(iA.w & 0x1FFFF, N_NODES - 1);
            int s4 = min(iB.x & 0x1FFFF, N_NODES - 1);
            int s5 = min(iB.y & 0x1FFFF, N_NODES - 1);
            int s6 = min(iB.z & 0x1FFFF, N_NODES - 1);
            int s7 = min(iB.w & 0x1FFFF, N_NODES - 1);
            uint4 r0 = *(const uint4*)(h + (size_t)s0 * DIM + ln16 * 8);
            uint4 r1 = *(const uint4*)(h + (size_t)s1 * DIM + ln16 * 8);
            uint4 r2 = *(const uint4*)(h + (size_t)s2 * DIM + ln16 * 8);
            uint4 r3 = *(const uint4*)(h + (size_t)s3 * DIM + ln16 * 8);
            uint4 r4 = *(const uint4*)(h + (size_t)s4 * DIM + ln16 * 8);
            uint4 r5 = *(const uint4*)(h + (size_t)s5 * DIM + ln16 * 8);
            uint4 r6 = *(const uint4*)(h + (size_t)s6 * DIM + ln16 * 8);
            uint4 r7 = *(const uint4*)(h + (size_t)s7 * DIM + ln16 * 8);
#define ACC(RK, K)                                                        \
            {                                                             \
                unsigned w0 = (e + (K) < dgv) ? RK.x : 0u;                \
                unsigned w1 = (e + (K) < dgv) ? RK.y : 0u;                \
                unsigned w2 = (e + (K) < dgv) ? RK.z : 0u;                \
                unsigned w3 = (e + (K) < dgv) ? RK.w : 0u;                \
                a0 += bflo(w0); a1 += bfhi(w0);                           \
                a2 += bflo(w1); a3 += bfhi(w1);                           \
                a4 += bflo(w2); a5 += bfhi(w2);                           \
                a6 += bflo(w3); a7 += bfhi(w3);                           \
            }
            ACC(r0, 0) ACC(r1, 1) ACC(r2, 2) ACC(r3, 3)
            ACC(r4, 4) ACC(r5, 5) ACC(r6, 6) ACC(r7, 7)
#undef ACC
        }

        uint4 o;
        o.x = f2bf_pack(a0, a1);
        o.y = f2bf_pack(a2, a3);
        o.z = f2bf_pack(a4, a5);
        o.w = f2bf_pack(a6, a7);
        *(uint4*)&buf[(wv * 16 + j * 4 + sub) * LSTRIDE + ln16 * 8] = o;
    }

    // ---- A1 fragments ----
    bf16x8 a1f[4];
    {
        const unsigned short* mr = buf + (wv * 16 + n) * LSTRIDE + q * 8;
#pragma unroll
        for (int kb = 0; kb < 4; ++kb) a1f[kb] = *(const bf16x8*)(mr + kb * 32);
    }

    float bia1[8], bia2[8];
#pragma unroll
    for (int ct = 0; ct < 8; ++ct) {
        bia1[ct] = b1[ct * 16 + n];
        bia2[ct] = b2[ct * 16 + n];
    }

    // ---- GEMM1 ----
#pragma unroll
    for (int ct = 0; ct < 8; ++ct) {
        f32x4 acc = {0.f, 0.f, 0.f, 0.f};
#pragma unroll
        for (int kb = 0; kb < 4; ++kb) {
            bf16x8 b = *(const bf16x8*)(Wp1 + kb * 4096 + (ct * 16 + n) * 32 + q * 8);
            acc = __builtin_amdgcn_mfma_f32_16x16x32_bf16(a1f[kb], b, acc, 0, 0, 0);
        }
#pragma unroll
        for (int r = 0; r < 4; ++r)
            buf[(wv * 16 + q * 4 + r) * LSTRIDE + ct * 16 + n] =
                f2bf(fmaxf(acc[r] + bia1[ct], 0.f));
    }

    // ---- A2 fragments ----
    bf16x8 a2f[4];
    {
        const unsigned short* tr = buf + (wv * 16 + n) * LSTRIDE + q * 8;
#pragma unroll
        for (int kb = 0; kb < 4; ++kb) a2f[kb] = *(const bf16x8*)(tr + kb * 32);
    }

    // ---- GEMM2 ----
#pragma unroll
    for (int ct = 0; ct < 8; ++ct) {
        f32x4 acc = {0.f, 0.f, 0.f, 0.f};
#pragma unroll
        for (int kb = 0; kb < 4; ++kb) {
            bf16x8 b = *(const bf16x8*)(Wp2 + kb * 4096 + (ct * 16 + n) * 32 + q * 8);
            acc = __builtin_amdgcn_mfma_f32_16x16x32_bf16(a2f[kb], b, acc, 0, 0, 0);
        }
#pragma unroll
        for (int r = 0; r < 4; ++r) {
            float v = acc[r] + bia2[ct];
            if (relu_out) v = fmaxf(v, 0.f);
            buf[(wv * 16 + q * 4 + r) * LSTRIDE + ct * 16 + n] = f2bf(v);
        }
    }

    // ---- store own wave's 16 rows ----
    {
#pragma unroll
        for (int s2 = 0; s2 < 4; ++s2) {
            int lr = wv * 16 + s2 * 4 + (lane >> 4);
            int c0 = (lane & 15) * 8;
            *(bf16x8*)(hout + (size_t)(row0 + lr) * DIM + c0) =
                *(const bf16x8*)(buf + lr * LSTRIDE + c0);
        }
    }
}

// ---------------- pool ----------------
__global__ void k_starts(const int* __restrict__ batch, int* __restrict__ starts) {
    int g = threadIdx.x;
    if (g > NGRAPHS) return;
    int lo = 0, hi = N_NODES;
    while (lo < hi) {
        int mid = (lo + hi) >> 1;
        if (batch[mid] < g) lo = mid + 1;
        else hi = mid;
    }
    starts[g] = lo;
}

// stage 1: block (g, c) covers row residues i0 + c*4 + rowpar (mod 64).
__global__ __launch_bounds__(256) void k_pool1(const unsigned short* __restrict__ h,
                                               const int* __restrict__ starts,
                                               float* __restrict__ partial) {
    __shared__ float red[4][DIM];
    int g = blockIdx.x, c = blockIdx.y;
    int t = threadIdx.x;
    int rowpar = t >> 6;
    int col = (t & 63) * 2;
    int i0 = starts[g], i1 = starts[g + 1];
    float mx = -FLT_MAX, my = -FLT_MAX;
    for (int i = i0 + c * 4 + rowpar; i < i1; i += 64) {
        unsigned u = *(const unsigned*)(h + (size_t)i * DIM + col);
        mx = fmaxf(mx, bflo(u));
        my = fmaxf(my, bfhi(u));
    }
    red[rowpar][col] = mx;
    red[rowpar][col + 1] = my;
    __syncthreads();
    if (rowpar == 0) {
        mx = fmaxf(fmaxf(red[0][col], red[1][col]), fmaxf(red[2][col], red[3][col]));
        my = fmaxf(fmaxf(red[0][col + 1], red[1][col + 1]),
                   fmaxf(red[2][col + 1], red[3][col + 1]));
        float* p = partial + ((size_t)g * PCHUNK + c) * DIM;
        p[col] = mx;
        p[col + 1] = my;
    }
}

// stage 2: fold the 16 partials per graph.
__global__ __launch_bounds__(128) void k_pool2(const float* __restrict__ partial,
                                               float* __restrict__ out) {
    int g = blockIdx.x;
    int col = threadIdx.x;
    const float* p = partial + (size_t)g * PCHUNK * DIM + col;
    float m = p[0];
#pragma unroll
    for (int c = 1; c < PCHUNK; ++c) m = fmaxf(m, p[c * DIM]);
    out[g * DIM + col] = m;
}

extern "C" void kernel_launch(void* const* d_in, const int* in_sizes, int n_in,
                              void* d_out, int out_size, void* d_ws, size_t ws_size,
                              hipStream_t stream) {
    const float* x   = (const float*)d_in[0];
    const int* ei    = (const int*)d_in[1];
    const int* batch = (const int*)d_in[2];
    const float* W1  = (const float*)d_in[3];
    const float* b1  = (const float*)d_in[4];
    const float* W2  = (const float*)d_in[5];
    const float* b2  = (const float*)d_in[6];
    float* out = (float*)d_out;

    const int* src = ei;
    const int* dst = ei + N_EDGES;

    unsigned short* hA  = (unsigned short*)d_ws;                   // 25.6 MB
    unsigned short* hB  = hA + (size_t)N_NODES * DIM;              // 25.6 MB
    unsigned* store     = (unsigned*)(hB + (size_t)N_NODES * DIM); // 8.0 MB
    int* ssrc           = (int*)(store + (size_t)NBUCK * BCAP);    // 9.6 MB
    int* offs           = ssrc + (size_t)NBUCK * CCAP + 64;        // 400 KB
    int* deg            = offs + N_NODES;                          // 400 KB
    int* gcnt           = deg + N_NODES;                           // NBUCK
    unsigned short* wpk = (unsigned short*)(gcnt + NBUCK);         // 192 KB
    int* starts         = (int*)(wpk + 6 * DIM * DIM);             // 65
    float* partial      = (float*)(starts + NGRAPHS + 1);          // 512 KB

    // bucketed CSR build
    k_zero_gcnt<<<2, 256, 0, stream>>>(gcnt);
    k_bucket<<<(N_EDGES + EPB - 1) / EPB, 256, 0, stream>>>(src, dst, gcnt, store);
    k_csr<<<NBUCK, 256, 0, stream>>>(store, gcnt, offs, deg, ssrc);

    // dtype prep
    k_cast<<<(N_NODES * DIM / 4 + 255) / 256, 256, 0, stream>>>(x, hA);
    k_pack<<<(6 * DIM * DIM + 255) / 256, 256, 0, stream>>>(W1, W2, wpk);

    const int fusedBlocks = N_NODES / BROWS;   // 3125 exactly
    unsigned short* Wp1 = wpk;
    unsigned short* Wp2 = wpk + 3 * DIM * DIM;

    // 3 fused layers, ping-pong hA <-> hB
    k_fused<<<fusedBlocks, 128, 0, stream>>>(hA, offs, deg, ssrc, hB,
                                             Wp1, b1, Wp2, b2, 1);
    k_fused<<<fusedBlocks, 128, 0, stream>>>(hB, offs, deg, ssrc, hA,
                                             Wp1 + DIM * DIM, b1 + DIM,
                                             Wp2 + DIM * DIM, b2 + DIM, 1);
    k_fused<<<fusedBlocks, 128, 0, stream>>>(hA, offs, deg, ssrc, hB,
                                             Wp1 + 2 * DIM * DIM, b1 + 2 * DIM,
                                             Wp2 + 2 * DIM * DIM, b2 + 2 * DIM, 0);

    // two-stage pool
    k_starts<<<1, 128, 0, stream>>>(batch, starts);
    {
        dim3 g1(NGRAPHS, PCHUNK);
        k_pool1<<<g1, 256, 0, stream>>>(hB, starts, partial);
        k_pool2<<<NGRAPHS, 128, 0, stream>>>(partial, out);
    }
}

// Round 9
// 392.175 us; speedup vs baseline: 2.2149x; 1.0266x over previous
//
#include <hip/hip_runtime.h>
#include <float.h>

// PretrainingGIN on MI355X — Round 9.
// R8 post-mortem: k_fused FETCH=217MB is the 8-XCD compulsory replication
// floor; rate 2.7-3.0 TB/s at 37% occupancy (LDS-bound). Probe: halve idx
// staging (IDXCAP 512, 14-sigma safe) -> 12.7KB/block -> ~2x waves. Also:
// bucket+cast+pack merged into one super-prep kernel (independent work,
// overlapped, -2 launches); k_starts folded into k_pool1 (-1 launch).

#define N_NODES 100000
#define N_EDGES 1600000
#define DIM 128
#define NGRAPHS 64
#define PCHUNK 16          // pool stage-1 chunks per graph

#define NBUCK 391          // ceil(100000/256) buckets of 256 nodes
#define BCAP 5120          // max edges/bucket (mean 4096, +16 sigma)
#define CCAP 6144          // ssrc ints per bucket (edges + per-node align pad)
#define EPT 8              // edges per thread in bucket pass
#define EPB 2048           // 256*8 edges per block

#define NB_BUCKET ((N_EDGES + EPB - 1) / EPB)          // 782
#define NB_CAST   (N_NODES * DIM / 4 / 256)            // 12500
#define NB_PACK   (6 * DIM * DIM / 256)                // 384

#define BROWS 32           // rows per fused block (16 per wave, 2 waves)
#define LSTRIDE 136        // bf16 elems; 272B rows keep 16B align
#define IDXCAP 512         // staged indices per wave (sum deg ~280, 14-sigma)

typedef __attribute__((ext_vector_type(8))) short bf16x8;
typedef __attribute__((ext_vector_type(4))) float f32x4;

__device__ inline float bflo(unsigned u) { return __uint_as_float(u << 16); }
__device__ inline float bfhi(unsigned u) { return __uint_as_float(u & 0xffff0000u); }

__device__ inline unsigned short f2bf(float a) {      // RNE
    unsigned u = __float_as_uint(a);
    u = u + 0x7fff + ((u >> 16) & 1);
    return (unsigned short)(u >> 16);
}
__device__ inline unsigned f2bf_pack(float a, float b) {
    unsigned ua = __float_as_uint(a), ub = __float_as_uint(b);
    ua = ua + 0x7fff + ((ua >> 16) & 1);
    ub = ub + 0x7fff + ((ub >> 16) & 1);
    return (ua >> 16) | (ub & 0xffff0000u);
}

__global__ void k_zero_gcnt(int* __restrict__ gcnt) {
    int i = blockIdx.x * blockDim.x + threadIdx.x;
    if (i < NBUCK) gcnt[i] = 0;
}

// ---------------- super-prep: bucket | cast | pack (independent) ----------------
__global__ __launch_bounds__(256) void k_prep(const int* __restrict__ src,
                                              const int* __restrict__ dst,
                                              int* __restrict__ gcnt,
                                              unsigned* __restrict__ store,
                                              const float* __restrict__ x,
                                              unsigned short* __restrict__ hA,
                                              const float* __restrict__ W1,
                                              const float* __restrict__ W2,
                                              unsigned short* __restrict__ pack) {
    __shared__ int hist[NBUCK];
    __shared__ int base[NBUCK];
    const int t = threadIdx.x;
    const int b = blockIdx.x;

    if (b < NB_BUCKET) {
        // ---- bucket the edges ----
        const int e0 = b * EPB;
        for (int i = t; i < NBUCK; i += 256) hist[i] = 0;
        __syncthreads();

        int bk[EPT], rk[EPT];
        unsigned pk[EPT];
#pragma unroll
        for (int k = 0; k < EPT; ++k) {
            int e = e0 + k * 256 + t;
            bk[k] = -1;
            if (e < N_EDGES) {
                int d = dst[e];
                int s = src[e];
                int bb = d >> 8;
                bk[k] = bb;
                rk[k] = atomicAdd(&hist[bb], 1);
                pk[k] = ((unsigned)(d & 255) << 17) | (unsigned)s;
            }
        }
        __syncthreads();
        for (int i = t; i < NBUCK; i += 256)
            if (hist[i] > 0) base[i] = atomicAdd(&gcnt[i], hist[i]);
        __syncthreads();
#pragma unroll
        for (int k = 0; k < EPT; ++k) {
            if (bk[k] >= 0) {
                int p = base[bk[k]] + rk[k];
                if (p < BCAP) store[(size_t)bk[k] * BCAP + p] = pk[k];
            }
        }
    } else if (b < NB_BUCKET + NB_CAST) {
        // ---- cast x -> bf16 ----
        int i = ((b - NB_BUCKET) * 256 + t) * 4;
        float4 v = *(const float4*)(x + i);
        uint2 o;
        o.x = f2bf_pack(v.x, v.y);
        o.y = f2bf_pack(v.z, v.w);
        *(uint2*)(hA + i) = o;
    } else {
        // ---- repack W into B-fragment order bf16 ----
        int tid = (b - NB_BUCKET - NB_CAST) * 256 + t;
        int mat = tid >> 14;
        int e = tid & 16383;
        int k = e >> 7, c = e & 127;
        const float* W = (mat < 3) ? (W1 + mat * DIM * DIM)
                                   : (W2 + (mat - 3) * DIM * DIM);
        int kb = k >> 5, q = (k >> 3) & 3, j = k & 7;
        pack[mat * DIM * DIM + kb * 4096 + c * 32 + q * 8 + j] = f2bf(W[k * DIM + c]);
    }
}

// ---------------- build pass B: per-bucket CSR fill ----------------
__global__ __launch_bounds__(256) void k_csr(const unsigned* __restrict__ store,
                                             const int* __restrict__ gcnt,
                                             int* __restrict__ offs,
                                             int* __restrict__ deg,
                                             int* __restrict__ ssrc) {
    __shared__ int hist[256];
    __shared__ int s[256];
    __shared__ int pos[256];
    const int b = blockIdx.x;
    const int t = threadIdx.x;
    int nE = gcnt[b];
    if (nE > BCAP) nE = BCAP;

    hist[t] = 0;
    __syncthreads();
    const unsigned* bs = store + (size_t)b * BCAP;
    for (int e = t; e < nE; e += 256)
        atomicAdd(&hist[bs[e] >> 17], 1);
    __syncthreads();

    int cnt = hist[t];
    int al = (cnt + 3) & ~3;          // 16B-align each node's segment
    s[t] = al;
    __syncthreads();
    for (int off = 1; off < 256; off <<= 1) {
        int x = (t >= off) ? s[t - off] : 0;
        __syncthreads();
        s[t] += x;
        __syncthreads();
    }
    int loc = s[t] - al;              // exclusive prefix
    int node = b * 256 + t;
    if (node < N_NODES) {
        offs[node] = b * CCAP + loc;
        deg[node] = cnt;
    }
    pos[t] = loc;
    __syncthreads();

    int* out = ssrc + (size_t)b * CCAP;
    for (int e = t; e < nE; e += 256) {
        unsigned p = bs[e];
        int dl = p >> 17;
        int q = atomicAdd(&pos[dl], 1);
        out[q] = (int)(p & 0x1FFFFu);
    }
}

// ---------------- fused layer: h_out = MLP(h + sum_{j->i} h_j) ----------------
__global__ __launch_bounds__(128) void k_fused(const unsigned short* __restrict__ h,
                                               const int* __restrict__ offs,
                                               const int* __restrict__ deg,
                                               const int* __restrict__ ssrc,
                                               unsigned short* __restrict__ hout,
                                               const unsigned short* __restrict__ Wp1,
                                               const float* __restrict__ b1,
                                               const unsigned short* __restrict__ Wp2,
                                               const float* __restrict__ b2,
                                               int relu_out) {
    __shared__ int idx[2][IDXCAP];                    // 4096 B
    __shared__ unsigned short buf[BROWS * LSTRIDE];   // 8704 B
    const int tid = threadIdx.x;
    const int wv = tid >> 6, lane = tid & 63;
    const int q = lane >> 4, n = lane & 15;
    const int sub = lane >> 4, ln16 = lane & 15;
    const int row0 = blockIdx.x * BROWS;
    const int nb0 = row0 + wv * 16;                   // wave's first node

    // ---- stage the wave's indices (contiguous CSR range) into LDS ----
    const int base0 = offs[nb0];
    int cnt = offs[nb0 + 15] + deg[nb0 + 15] - base0;
    if (cnt > IDXCAP) cnt = IDXCAP;
    for (int i = lane * 4; i < cnt; i += 256) {
        int4 v = *(const int4*)(ssrc + base0 + i);
        *(int4*)&idx[wv][i] = v;
    }

    // ---- gather: 4 iterations x 4 parallel rows ----
#pragma unroll 1
    for (int j = 0; j < 4; ++j) {
        const int node = nb0 + j * 4 + sub;
        const unsigned short* hb = h + (size_t)node * DIM + ln16 * 8;
        uint4 sv = *(const uint4*)hb;
        float a0 = bflo(sv.x), a1 = bfhi(sv.x);
        float a2 = bflo(sv.y), a3 = bfhi(sv.y);
        float a4 = bflo(sv.z), a5 = bfhi(sv.z);
        float a6 = bflo(sv.w), a7 = bfhi(sv.w);

        const int loc = offs[node] - base0;
        const int dgv = deg[node];
        int m1 = max(dgv, __shfl_xor(dgv, 16));
        int mx = max(m1, __shfl_xor(m1, 32));

        for (int e = 0; e < mx; e += 8) {
            int ebase = loc + e;
            if (ebase > IDXCAP - 8) ebase = IDXCAP - 8;   // clamp (never in practice)
            int4 iA = *(const int4*)&idx[wv][ebase];
            int4 iB = *(const int4*)&idx[wv][ebase + 4];
            int s0 = min(iA.x & 0x1FFFF, N_NODES - 1);
            int s1 = min(iA.y & 0x1FFFF, N_NODES - 1);
            int s2 = min(iA.z & 0x1FFFF, N_NODES - 1);
            int s3 = min(iA.w & 0x1FFFF, N_NODES - 1);
            int s4 = min(iB.x & 0x1FFFF, N_NODES - 1);
            int s5 = min(iB.y & 0x1FFFF, N_NODES - 1);
            int s6 = min(iB.z & 0x1FFFF, N_NODES - 1);
            int s7 = min(iB.w & 0x1FFFF, N_NODES - 1);
            uint4 r0 = *(const uint4*)(h + (size_t)s0 * DIM + ln16 * 8);
            uint4 r1 = *(const uint4*)(h + (size_t)s1 * DIM + ln16 * 8);
            uint4 r2 = *(const uint4*)(h + (size_t)s2 * DIM + ln16 * 8);
            uint4 r3 = *(const uint4*)(h + (size_t)s3 * DIM + ln16 * 8);
            uint4 r4 = *(const uint4*)(h + (size_t)s4 * DIM + ln16 * 8);
            uint4 r5 = *(const uint4*)(h + (size_t)s5 * DIM + ln16 * 8);
            uint4 r6 = *(const uint4*)(h + (size_t)s6 * DIM + ln16 * 8);
            uint4 r7 = *(const uint4*)(h + (size_t)s7 * DIM + ln16 * 8);
#define ACC(RK, K)                                                        \
            {                                                             \
                unsigned w0 = (e + (K) < dgv) ? RK.x : 0u;                \
                unsigned w1 = (e + (K) < dgv) ? RK.y : 0u;                \
                unsigned w2 = (e + (K) < dgv) ? RK.z : 0u;                \
                unsigned w3 = (e + (K) < dgv) ? RK.w : 0u;                \
                a0 += bflo(w0); a1 += bfhi(w0);                           \
                a2 += bflo(w1); a3 += bfhi(w1);                           \
                a4 += bflo(w2); a5 += bfhi(w2);                           \
                a6 += bflo(w3); a7 += bfhi(w3);                           \
            }
            ACC(r0, 0) ACC(r1, 1) ACC(r2, 2) ACC(r3, 3)
            ACC(r4, 4) ACC(r5, 5) ACC(r6, 6) ACC(r7, 7)
#undef ACC
        }

        uint4 o;
        o.x = f2bf_pack(a0, a1);
        o.y = f2bf_pack(a2, a3);
        o.z = f2bf_pack(a4, a5);
        o.w = f2bf_pack(a6, a7);
        *(uint4*)&buf[(wv * 16 + j * 4 + sub) * LSTRIDE + ln16 * 8] = o;
    }

    // ---- A1 fragments ----
    bf16x8 a1f[4];
    {
        const unsigned short* mr = buf + (wv * 16 + n) * LSTRIDE + q * 8;
#pragma unroll
        for (int kb = 0; kb < 4; ++kb) a1f[kb] = *(const bf16x8*)(mr + kb * 32);
    }

    float bia1[8], bia2[8];
#pragma unroll
    for (int ct = 0; ct < 8; ++ct) {
        bia1[ct] = b1[ct * 16 + n];
        bia2[ct] = b2[ct * 16 + n];
    }

    // ---- GEMM1 ----
#pragma unroll
    for (int ct = 0; ct < 8; ++ct) {
        f32x4 acc = {0.f, 0.f, 0.f, 0.f};
#pragma unroll
        for (int kb = 0; kb < 4; ++kb) {
            bf16x8 b = *(const bf16x8*)(Wp1 + kb * 4096 + (ct * 16 + n) * 32 + q * 8);
            acc = __builtin_amdgcn_mfma_f32_16x16x32_bf16(a1f[kb], b, acc, 0, 0, 0);
        }
#pragma unroll
        for (int r = 0; r < 4; ++r)
            buf[(wv * 16 + q * 4 + r) * LSTRIDE + ct * 16 + n] =
                f2bf(fmaxf(acc[r] + bia1[ct], 0.f));
    }

    // ---- A2 fragments ----
    bf16x8 a2f[4];
    {
        const unsigned short* tr = buf + (wv * 16 + n) * LSTRIDE + q * 8;
#pragma unroll
        for (int kb = 0; kb < 4; ++kb) a2f[kb] = *(const bf16x8*)(tr + kb * 32);
    }

    // ---- GEMM2 ----
#pragma unroll
    for (int ct = 0; ct < 8; ++ct) {
        f32x4 acc = {0.f, 0.f, 0.f, 0.f};
#pragma unroll
        for (int kb = 0; kb < 4; ++kb) {
            bf16x8 b = *(const bf16x8*)(Wp2 + kb * 4096 + (ct * 16 + n) * 32 + q * 8);
            acc = __builtin_amdgcn_mfma_f32_16x16x32_bf16(a2f[kb], b, acc, 0, 0, 0);
        }
#pragma unroll
        for (int r = 0; r < 4; ++r) {
            float v = acc[r] + bia2[ct];
            if (relu_out) v = fmaxf(v, 0.f);
            buf[(wv * 16 + q * 4 + r) * LSTRIDE + ct * 16 + n] = f2bf(v);
        }
    }

    // ---- store own wave's 16 rows ----
    {
#pragma unroll
        for (int s2 = 0; s2 < 4; ++s2) {
            int lr = wv * 16 + s2 * 4 + (lane >> 4);
            int c0 = (lane & 15) * 8;
            *(bf16x8*)(hout + (size_t)(row0 + lr) * DIM + c0) =
                *(const bf16x8*)(buf + lr * LSTRIDE + c0);
        }
    }
}

// ---------------- pool (starts fused into stage 1) ----------------
__device__ inline int lbound(const int* __restrict__ batch, int g) {
    int lo = 0, hi = N_NODES;
    while (lo < hi) {
        int mid = (lo + hi) >> 1;
        if (batch[mid] < g) lo = mid + 1;
        else hi = mid;
    }
    return lo;
}

__global__ __launch_bounds__(256) void k_pool1(const unsigned short* __restrict__ h,
                                               const int* __restrict__ batch,
                                               float* __restrict__ partial) {
    __shared__ float red[4][DIM];
    __shared__ int sb[2];
    int g = blockIdx.x, c = blockIdx.y;
    int t = threadIdx.x;
    if (t < 2) sb[t] = lbound(batch, g + t);
    __syncthreads();
    int i0 = sb[0], i1 = sb[1];
    int rowpar = t >> 6;
    int col = (t & 63) * 2;
    float mx = -FLT_MAX, my = -FLT_MAX;
    for (int i = i0 + c * 4 + rowpar; i < i1; i += 64) {
        unsigned u = *(const unsigned*)(h + (size_t)i * DIM + col);
        mx = fmaxf(mx, bflo(u));
        my = fmaxf(my, bfhi(u));
    }
    red[rowpar][col] = mx;
    red[rowpar][col + 1] = my;
    __syncthreads();
    if (rowpar == 0) {
        mx = fmaxf(fmaxf(red[0][col], red[1][col]), fmaxf(red[2][col], red[3][col]));
        my = fmaxf(fmaxf(red[0][col + 1], red[1][col + 1]),
                   fmaxf(red[2][col + 1], red[3][col + 1]));
        float* p = partial + ((size_t)g * PCHUNK + c) * DIM;
        p[col] = mx;
        p[col + 1] = my;
    }
}

__global__ __launch_bounds__(128) void k_pool2(const float* __restrict__ partial,
                                               float* __restrict__ out) {
    int g = blockIdx.x;
    int col = threadIdx.x;
    const float* p = partial + (size_t)g * PCHUNK * DIM + col;
    float m = p[0];
#pragma unroll
    for (int c = 1; c < PCHUNK; ++c) m = fmaxf(m, p[c * DIM]);
    out[g * DIM + col] = m;
}

extern "C" void kernel_launch(void* const* d_in, const int* in_sizes, int n_in,
                              void* d_out, int out_size, void* d_ws, size_t ws_size,
                              hipStream_t stream) {
    const float* x   = (const float*)d_in[0];
    const int* ei    = (const int*)d_in[1];
    const int* batch = (const int*)d_in[2];
    const float* W1  = (const float*)d_in[3];
    const float* b1  = (const float*)d_in[4];
    const float* W2  = (const float*)d_in[5];
    const float* b2  = (const float*)d_in[6];
    float* out = (float*)d_out;

    const int* src = ei;
    const int* dst = ei + N_EDGES;

    unsigned short* hA  = (unsigned short*)d_ws;                   // 25.6 MB
    unsigned short* hB  = hA + (size_t)N_NODES * DIM;              // 25.6 MB
    unsigned* store     = (unsigned*)(hB + (size_t)N_NODES * DIM); // 8.0 MB
    int* ssrc           = (int*)(store + (size_t)NBUCK * BCAP);    // 9.6 MB
    int* offs           = ssrc + (size_t)NBUCK * CCAP + 64;        // 400 KB
    int* deg            = offs + N_NODES;                          // 400 KB
    int* gcnt           = deg + N_NODES;                           // NBUCK
    unsigned short* wpk = (unsigned short*)(gcnt + NBUCK);         // 192 KB
    float* partial      = (float*)(wpk + 6 * DIM * DIM);           // 512 KB

    // prep: zero, then fused bucket|cast|pack, then per-bucket CSR
    k_zero_gcnt<<<2, 256, 0, stream>>>(gcnt);
    k_prep<<<NB_BUCKET + NB_CAST + NB_PACK, 256, 0, stream>>>(
        src, dst, gcnt, store, x, hA, W1, W2, wpk);
    k_csr<<<NBUCK, 256, 0, stream>>>(store, gcnt, offs, deg, ssrc);

    const int fusedBlocks = N_NODES / BROWS;   // 3125 exactly
    unsigned short* Wp1 = wpk;
    unsigned short* Wp2 = wpk + 3 * DIM * DIM;

    // 3 fused layers, ping-pong hA <-> hB
    k_fused<<<fusedBlocks, 128, 0, stream>>>(hA, offs, deg, ssrc, hB,
                                             Wp1, b1, Wp2, b2, 1);
    k_fused<<<fusedBlocks, 128, 0, stream>>>(hB, offs, deg, ssrc, hA,
                                             Wp1 + DIM * DIM, b1 + DIM,
                                             Wp2 + DIM * DIM, b2 + DIM, 1);
    k_fused<<<fusedBlocks, 128, 0, stream>>>(hA, offs, deg, ssrc, hB,
                                             Wp1 + 2 * DIM * DIM, b1 + 2 * DIM,
                                             Wp2 + 2 * DIM * DIM, b2 + 2 * DIM, 0);

    // two-stage pool (starts computed inline in stage 1)
    {
        dim3 g1(NGRAPHS, PCHUNK);
        k_pool1<<<g1, 256, 0, stream>>>(hB, batch, partial);
        k_pool2<<<NGRAPHS, 128, 0, stream>>>(partial, out);
    }
}

// Round 10
// 370.898 us; speedup vs baseline: 2.3420x; 1.0574x over previous
//
#include <hip/hip_runtime.h>
#include <float.h>

// PretrainingGIN on MI355X — Round 10.
// R9 post-mortem: gather rate ~3 TB/s is concurrency-saturated (occupancy probe
// moved nothing) => attack BYTES. Wave-max loop bound over 4 nodes caused ~30%
// of row loads to run past each node's own degree into the NEXT node's srcs
// (real random fetch, masked in acc). Fix: per-subgroup (node-uniform) bounds —
// 8-chunks strictly inside the node's 4-aligned CSR segment + one 4-chunk tail;
// finished subgroups are exec-masked and issue no loads; pad slots are a
// constant poison row (one hot line, ~free).
// Also: hipMemsetAsync replaces k_zero_gcnt (-1 launch).

#define N_NODES 100000
#define N_EDGES 1600000
#define DIM 128
#define NGRAPHS 64
#define PCHUNK 16          // pool stage-1 chunks per graph

#define NBUCK 391          // ceil(100000/256) buckets of 256 nodes
#define BCAP 5120          // max edges/bucket (mean 4096, +16 sigma)
#define CCAP 6144          // ssrc ints per bucket (edges + per-node align pad)
#define EPT 8              // edges per thread in bucket pass
#define EPB 2048           // 256*8 edges per block

#define NB_BUCKET ((N_EDGES + EPB - 1) / EPB)          // 782
#define NB_CAST   (N_NODES * DIM / 4 / 256)            // 12500
#define NB_PACK   (6 * DIM * DIM / 256)                // 384

#define BROWS 32           // rows per fused block (16 per wave, 2 waves)
#define LSTRIDE 136        // bf16 elems; 272B rows keep 16B align
#define IDXCAP 512         // staged indices per wave (sum deg ~280, 14-sigma)

typedef __attribute__((ext_vector_type(8))) short bf16x8;
typedef __attribute__((ext_vector_type(4))) float f32x4;

__device__ inline float bflo(unsigned u) { return __uint_as_float(u << 16); }
__device__ inline float bfhi(unsigned u) { return __uint_as_float(u & 0xffff0000u); }

__device__ inline unsigned short f2bf(float a) {      // RNE
    unsigned u = __float_as_uint(a);
    u = u + 0x7fff + ((u >> 16) & 1);
    return (unsigned short)(u >> 16);
}
__device__ inline unsigned f2bf_pack(float a, float b) {
    unsigned ua = __float_as_uint(a), ub = __float_as_uint(b);
    ua = ua + 0x7fff + ((ua >> 16) & 1);
    ub = ub + 0x7fff + ((ub >> 16) & 1);
    return (ua >> 16) | (ub & 0xffff0000u);
}

// ---------------- super-prep: bucket | cast | pack (independent) ----------------
__global__ __launch_bounds__(256) void k_prep(const int* __restrict__ src,
                                              const int* __restrict__ dst,
                                              int* __restrict__ gcnt,
                                              unsigned* __restrict__ store,
                                              const float* __restrict__ x,
                                              unsigned short* __restrict__ hA,
                                              const float* __restrict__ W1,
                                              const float* __restrict__ W2,
                                              unsigned short* __restrict__ pack) {
    __shared__ int hist[NBUCK];
    __shared__ int base[NBUCK];
    const int t = threadIdx.x;
    const int b = blockIdx.x;

    if (b < NB_BUCKET) {
        // ---- bucket the edges ----
        const int e0 = b * EPB;
        for (int i = t; i < NBUCK; i += 256) hist[i] = 0;
        __syncthreads();

        int bk[EPT], rk[EPT];
        unsigned pk[EPT];
#pragma unroll
        for (int k = 0; k < EPT; ++k) {
            int e = e0 + k * 256 + t;
            bk[k] = -1;
            if (e < N_EDGES) {
                int d = dst[e];
                int s = src[e];
                int bb = d >> 8;
                bk[k] = bb;
                rk[k] = atomicAdd(&hist[bb], 1);
                pk[k] = ((unsigned)(d & 255) << 17) | (unsigned)s;
            }
        }
        __syncthreads();
        for (int i = t; i < NBUCK; i += 256)
            if (hist[i] > 0) base[i] = atomicAdd(&gcnt[i], hist[i]);
        __syncthreads();
#pragma unroll
        for (int k = 0; k < EPT; ++k) {
            if (bk[k] >= 0) {
                int p = base[bk[k]] + rk[k];
                if (p < BCAP) store[(size_t)bk[k] * BCAP + p] = pk[k];
            }
        }
    } else if (b < NB_BUCKET + NB_CAST) {
        // ---- cast x -> bf16 ----
        int i = ((b - NB_BUCKET) * 256 + t) * 4;
        float4 v = *(const float4*)(x + i);
        uint2 o;
        o.x = f2bf_pack(v.x, v.y);
        o.y = f2bf_pack(v.z, v.w);
        *(uint2*)(hA + i) = o;
    } else {
        // ---- repack W into B-fragment order bf16 ----
        int tid = (b - NB_BUCKET - NB_CAST) * 256 + t;
        int mat = tid >> 14;
        int e = tid & 16383;
        int k = e >> 7, c = e & 127;
        const float* W = (mat < 3) ? (W1 + mat * DIM * DIM)
                                   : (W2 + (mat - 3) * DIM * DIM);
        int kb = k >> 5, q = (k >> 3) & 3, j = k & 7;
        pack[mat * DIM * DIM + kb * 4096 + c * 32 + q * 8 + j] = f2bf(W[k * DIM + c]);
    }
}

// ---------------- build pass B: per-bucket CSR fill ----------------
__global__ __launch_bounds__(256) void k_csr(const unsigned* __restrict__ store,
                                             const int* __restrict__ gcnt,
                                             int* __restrict__ offs,
                                             int* __restrict__ deg,
                                             int* __restrict__ ssrc) {
    __shared__ int hist[256];
    __shared__ int s[256];
    __shared__ int pos[256];
    const int b = blockIdx.x;
    const int t = threadIdx.x;
    int nE = gcnt[b];
    if (nE > BCAP) nE = BCAP;

    hist[t] = 0;
    __syncthreads();
    const unsigned* bs = store + (size_t)b * BCAP;
    for (int e = t; e < nE; e += 256)
        atomicAdd(&hist[bs[e] >> 17], 1);
    __syncthreads();

    int cnt = hist[t];
    int al = (cnt + 3) & ~3;          // 16B-align each node's segment
    s[t] = al;
    __syncthreads();
    for (int off = 1; off < 256; off <<= 1) {
        int x = (t >= off) ? s[t - off] : 0;
        __syncthreads();
        s[t] += x;
        __syncthreads();
    }
    int loc = s[t] - al;              // exclusive prefix
    int node = b * 256 + t;
    if (node < N_NODES) {
        offs[node] = b * CCAP + loc;
        deg[node] = cnt;
    }
    pos[t] = loc;
    __syncthreads();

    int* out = ssrc + (size_t)b * CCAP;
    for (int e = t; e < nE; e += 256) {
        unsigned p = bs[e];
        int dl = p >> 17;
        int q = atomicAdd(&pos[dl], 1);
        out[q] = (int)(p & 0x1FFFFu);
    }
}

// ---------------- fused layer: h_out = MLP(h + sum_{j->i} h_j) ----------------
__global__ __launch_bounds__(128) void k_fused(const unsigned short* __restrict__ h,
                                               const int* __restrict__ offs,
                                               const int* __restrict__ deg,
                                               const int* __restrict__ ssrc,
                                               unsigned short* __restrict__ hout,
                                               const unsigned short* __restrict__ Wp1,
                                               const float* __restrict__ b1,
                                               const unsigned short* __restrict__ Wp2,
                                               const float* __restrict__ b2,
                                               int relu_out) {
    __shared__ int idx[2][IDXCAP];                    // 4096 B
    __shared__ unsigned short buf[BROWS * LSTRIDE];   // 8704 B
    const int tid = threadIdx.x;
    const int wv = tid >> 6, lane = tid & 63;
    const int q = lane >> 4, n = lane & 15;
    const int sub = lane >> 4, ln16 = lane & 15;
    const int row0 = blockIdx.x * BROWS;
    const int nb0 = row0 + wv * 16;                   // wave's first node

    // ---- stage the wave's indices (contiguous CSR range) into LDS ----
    const int base0 = offs[nb0];
    int cnt = offs[nb0 + 15] + deg[nb0 + 15] - base0;
    if (cnt > IDXCAP) cnt = IDXCAP;
    for (int i = lane * 4; i < cnt; i += 256) {
        int4 v = *(const int4*)(ssrc + base0 + i);
        *(int4*)&idx[wv][i] = v;
    }

    // ---- gather: 4 iterations x 4 parallel rows; PER-NODE loop bounds ----
#pragma unroll 1
    for (int j = 0; j < 4; ++j) {
        const int node = nb0 + j * 4 + sub;
        const unsigned short* hb = h + (size_t)node * DIM + ln16 * 8;
        uint4 sv = *(const uint4*)hb;
        float a0 = bflo(sv.x), a1 = bfhi(sv.x);
        float a2 = bflo(sv.y), a3 = bfhi(sv.y);
        float a4 = bflo(sv.z), a5 = bfhi(sv.z);
        float a6 = bflo(sv.w), a7 = bfhi(sv.w);

        int loc = offs[node] - base0;                 // 4-aligned
        const int dgv = deg[node];
        const int bound4 = (dgv + 3) & ~3;            // node's own segment
        if (loc > IDXCAP - 8) loc = IDXCAP - 8;       // safety (never in practice)

#define ACC(RK, K)                                                        \
            {                                                             \
                unsigned w0 = (e + (K) < dgv) ? RK.x : 0u;                \
                unsigned w1 = (e + (K) < dgv) ? RK.y : 0u;                \
                unsigned w2 = (e + (K) < dgv) ? RK.z : 0u;                \
                unsigned w3 = (e + (K) < dgv) ? RK.w : 0u;                \
                a0 += bflo(w0); a1 += bfhi(w0);                           \
                a2 += bflo(w1); a3 += bfhi(w1);                           \
                a4 += bflo(w2); a5 += bfhi(w2);                           \
                a6 += bflo(w3); a7 += bfhi(w3);                           \
            }

        int e = 0;
        for (; e + 8 <= bound4; e += 8) {             // fully inside segment
            int4 iA = *(const int4*)&idx[wv][loc + e];
            int4 iB = *(const int4*)&idx[wv][loc + e + 4];
            int s0 = min(iA.x & 0x1FFFF, N_NODES - 1);
            int s1 = min(iA.y & 0x1FFFF, N_NODES - 1);
            int s2 = min(iA.z & 0x1FFFF, N_NODES - 1);
            int s3 = min(iA.w & 0x1FFFF, N_NODES - 1);
            int s4 = min(iB.x & 0x1FFFF, N_NODES - 1);
            int s5 = min(iB.y & 0x1FFFF, N_NODES - 1);
            int s6 = min(iB.z & 0x1FFFF, N_NODES - 1);
            int s7 = min(iB.w & 0x1FFFF, N_NODES - 1);
            uint4 r0 = *(const uint4*)(h + (size_t)s0 * DIM + ln16 * 8);
            uint4 r1 = *(const uint4*)(h + (size_t)s1 * DIM + ln16 * 8);
            uint4 r2 = *(const uint4*)(h + (size_t)s2 * DIM + ln16 * 8);
            uint4 r3 = *(const uint4*)(h + (size_t)s3 * DIM + ln16 * 8);
            uint4 r4 = *(const uint4*)(h + (size_t)s4 * DIM + ln16 * 8);
            uint4 r5 = *(const uint4*)(h + (size_t)s5 * DIM + ln16 * 8);
            uint4 r6 = *(const uint4*)(h + (size_t)s6 * DIM + ln16 * 8);
            uint4 r7 = *(const uint4*)(h + (size_t)s7 * DIM + ln16 * 8);
            ACC(r0, 0) ACC(r1, 1) ACC(r2, 2) ACC(r3, 3)
            ACC(r4, 4) ACC(r5, 5) ACC(r6, 6) ACC(r7, 7)
        }
        if (e < bound4) {                             // one 4-chunk tail
            int4 iA = *(const int4*)&idx[wv][loc + e];
            int s0 = min(iA.x & 0x1FFFF, N_NODES - 1);
            int s1 = min(iA.y & 0x1FFFF, N_NODES - 1);
            int s2 = min(iA.z & 0x1FFFF, N_NODES - 1);
            int s3 = min(iA.w & 0x1FFFF, N_NODES - 1);
            uint4 r0 = *(const uint4*)(h + (size_t)s0 * DIM + ln16 * 8);
            uint4 r1 = *(const uint4*)(h + (size_t)s1 * DIM + ln16 * 8);
            uint4 r2 = *(const uint4*)(h + (size_t)s2 * DIM + ln16 * 8);
            uint4 r3 = *(const uint4*)(h + (size_t)s3 * DIM + ln16 * 8);
            ACC(r0, 0) ACC(r1, 1) ACC(r2, 2) ACC(r3, 3)
        }
#undef ACC

        uint4 o;
        o.x = f2bf_pack(a0, a1);
        o.y = f2bf_pack(a2, a3);
        o.z = f2bf_pack(a4, a5);
        o.w = f2bf_pack(a6, a7);
        *(uint4*)&buf[(wv * 16 + j * 4 + sub) * LSTRIDE + ln16 * 8] = o;
    }

    // ---- A1 fragments ----
    bf16x8 a1f[4];
    {
        const unsigned short* mr = buf + (wv * 16 + n) * LSTRIDE + q * 8;
#pragma unroll
        for (int kb = 0; kb < 4; ++kb) a1f[kb] = *(const bf16x8*)(mr + kb * 32);
    }

    float bia1[8], bia2[8];
#pragma unroll
    for (int ct = 0; ct < 8; ++ct) {
        bia1[ct] = b1[ct * 16 + n];
        bia2[ct] = b2[ct * 16 + n];
    }

    // ---- GEMM1 ----
#pragma unroll
    for (int ct = 0; ct < 8; ++ct) {
        f32x4 acc = {0.f, 0.f, 0.f, 0.f};
#pragma unroll
        for (int kb = 0; kb < 4; ++kb) {
            bf16x8 b = *(const bf16x8*)(Wp1 + kb * 4096 + (ct * 16 + n) * 32 + q * 8);
            acc = __builtin_amdgcn_mfma_f32_16x16x32_bf16(a1f[kb], b, acc, 0, 0, 0);
        }
#pragma unroll
        for (int r = 0; r < 4; ++r)
            buf[(wv * 16 + q * 4 + r) * LSTRIDE + ct * 16 + n] =
                f2bf(fmaxf(acc[r] + bia1[ct], 0.f));
    }

    // ---- A2 fragments ----
    bf16x8 a2f[4];
    {
        const unsigned short* tr = buf + (wv * 16 + n) * LSTRIDE + q * 8;
#pragma unroll
        for (int kb = 0; kb < 4; ++kb) a2f[kb] = *(const bf16x8*)(tr + kb * 32);
    }

    // ---- GEMM2 ----
#pragma unroll
    for (int ct = 0; ct < 8; ++ct) {
        f32x4 acc = {0.f, 0.f, 0.f, 0.f};
#pragma unroll
        for (int kb = 0; kb < 4; ++kb) {
            bf16x8 b = *(const bf16x8*)(Wp2 + kb * 4096 + (ct * 16 + n) * 32 + q * 8);
            acc = __builtin_amdgcn_mfma_f32_16x16x32_bf16(a2f[kb], b, acc, 0, 0, 0);
        }
#pragma unroll
        for (int r = 0; r < 4; ++r) {
            float v = acc[r] + bia2[ct];
            if (relu_out) v = fmaxf(v, 0.f);
            buf[(wv * 16 + q * 4 + r) * LSTRIDE + ct * 16 + n] = f2bf(v);
        }
    }

    // ---- store own wave's 16 rows ----
    {
#pragma unroll
        for (int s2 = 0; s2 < 4; ++s2) {
            int lr = wv * 16 + s2 * 4 + (lane >> 4);
            int c0 = (lane & 15) * 8;
            *(bf16x8*)(hout + (size_t)(row0 + lr) * DIM + c0) =
                *(const bf16x8*)(buf + lr * LSTRIDE + c0);
        }
    }
}

// ---------------- pool (starts fused into stage 1) ----------------
__device__ inline int lbound(const int* __restrict__ batch, int g) {
    int lo = 0, hi = N_NODES;
    while (lo < hi) {
        int mid = (lo + hi) >> 1;
        if (batch[mid] < g) lo = mid + 1;
        else hi = mid;
    }
    return lo;
}

__global__ __launch_bounds__(256) void k_pool1(const unsigned short* __restrict__ h,
                                               const int* __restrict__ batch,
                                               float* __restrict__ partial) {
    __shared__ float red[4][DIM];
    __shared__ int sb[2];
    int g = blockIdx.x, c = blockIdx.y;
    int t = threadIdx.x;
    if (t < 2) sb[t] = lbound(batch, g + t);
    __syncthreads();
    int i0 = sb[0], i1 = sb[1];
    int rowpar = t >> 6;
    int col = (t & 63) * 2;
    float mx = -FLT_MAX, my = -FLT_MAX;
    for (int i = i0 + c * 4 + rowpar; i < i1; i += 64) {
        unsigned u = *(const unsigned*)(h + (size_t)i * DIM + col);
        mx = fmaxf(mx, bflo(u));
        my = fmaxf(my, bfhi(u));
    }
    red[rowpar][col] = mx;
    red[rowpar][col + 1] = my;
    __syncthreads();
    if (rowpar == 0) {
        mx = fmaxf(fmaxf(red[0][col], red[1][col]), fmaxf(red[2][col], red[3][col]));
        my = fmaxf(fmaxf(red[0][col + 1], red[1][col + 1]),
                   fmaxf(red[2][col + 1], red[3][col + 1]));
        float* p = partial + ((size_t)g * PCHUNK + c) * DIM;
        p[col] = mx;
        p[col + 1] = my;
    }
}

__global__ __launch_bounds__(128) void k_pool2(const float* __restrict__ partial,
                                               float* __restrict__ out) {
    int g = blockIdx.x;
    int col = threadIdx.x;
    const float* p = partial + (size_t)g * PCHUNK * DIM + col;
    float m = p[0];
#pragma unroll
    for (int c = 1; c < PCHUNK; ++c) m = fmaxf(m, p[c * DIM]);
    out[g * DIM + col] = m;
}

extern "C" void kernel_launch(void* const* d_in, const int* in_sizes, int n_in,
                              void* d_out, int out_size, void* d_ws, size_t ws_size,
                              hipStream_t stream) {
    const float* x   = (const float*)d_in[0];
    const int* ei    = (const int*)d_in[1];
    const int* batch = (const int*)d_in[2];
    const float* W1  = (const float*)d_in[3];
    const float* b1  = (const float*)d_in[4];
    const float* W2  = (const float*)d_in[5];
    const float* b2  = (const float*)d_in[6];
    float* out = (float*)d_out;

    const int* src = ei;
    const int* dst = ei + N_EDGES;

    unsigned short* hA  = (unsigned short*)d_ws;                   // 25.6 MB
    unsigned short* hB  = hA + (size_t)N_NODES * DIM;              // 25.6 MB
    unsigned* store     = (unsigned*)(hB + (size_t)N_NODES * DIM); // 8.0 MB
    int* ssrc           = (int*)(store + (size_t)NBUCK * BCAP);    // 9.6 MB
    int* offs           = ssrc + (size_t)NBUCK * CCAP + 64;        // 400 KB
    int* deg            = offs + N_NODES;                          // 400 KB
    int* gcnt           = deg + N_NODES;                           // NBUCK
    unsigned short* wpk = (unsigned short*)(gcnt + NBUCK);         // 192 KB
    float* partial      = (float*)(wpk + 6 * DIM * DIM);           // 512 KB

    // prep: async memset of gcnt, fused bucket|cast|pack, per-bucket CSR
    hipMemsetAsync(gcnt, 0, NBUCK * sizeof(int), stream);
    k_prep<<<NB_BUCKET + NB_CAST + NB_PACK, 256, 0, stream>>>(
        src, dst, gcnt, store, x, hA, W1, W2, wpk);
    k_csr<<<NBUCK, 256, 0, stream>>>(store, gcnt, offs, deg, ssrc);

    const int fusedBlocks = N_NODES / BROWS;   // 3125 exactly
    unsigned short* Wp1 = wpk;
    unsigned short* Wp2 = wpk + 3 * DIM * DIM;

    // 3 fused layers, ping-pong hA <-> hB
    k_fused<<<fusedBlocks, 128, 0, stream>>>(hA, offs, deg, ssrc, hB,
                                             Wp1, b1, Wp2, b2, 1);
    k_fused<<<fusedBlocks, 128, 0, stream>>>(hB, offs, deg, ssrc, hA,
                                             Wp1 + DIM * DIM, b1 + DIM,
                                             Wp2 + DIM * DIM, b2 + DIM, 1);
    k_fused<<<fusedBlocks, 128, 0, stream>>>(hA, offs, deg, ssrc, hB,
                                             Wp1 + 2 * DIM * DIM, b1 + 2 * DIM,
                                             Wp2 + 2 * DIM * DIM, b2 + 2 * DIM, 0);

    // two-stage pool (starts computed inline in stage 1)
    {
        dim3 g1(NGRAPHS, PCHUNK);
        k_pool1<<<g1, 256, 0, stream>>>(hB, batch, partial);
        k_pool2<<<NGRAPHS, 128, 0, stream>>>(partial, out);
    }
}